// Round 11
// baseline (2273.879 us; speedup 1.0000x reference)
//
#include <hip/hip_runtime.h>
#include <math.h>

#define HDIM 2048
#define SEQ 2048
#define NHEADS 32
#define KVH 8
#define HEADD 64
#define FDIM 8192
#define NLAYERS 4
#define VOCAB 32000

typedef __attribute__((ext_vector_type(4))) float f32x4;
typedef __attribute__((ext_vector_type(8))) short bf16x8;

__device__ __forceinline__ unsigned short f2b(float f) {
    unsigned int u = __float_as_uint(f);
    u += 0x7fff + ((u >> 16) & 1);   // round-to-nearest-even
    return (unsigned short)(u >> 16);
}

// bijective XCD-aware block swizzle [learn_hip m204]
__device__ __forceinline__ int xcd_swz(int bid, int nwg) {
    int xcd = bid & 7, lin = bid >> 3;
    int q = nwg >> 3, r = nwg & 7;
    return (xcd < r ? xcd * (q + 1) : r * (q + 1) + (xcd - r) * q) + lin;
}

#define GLL(gp, lp) __builtin_amdgcn_global_load_lds( \
    (const __attribute__((address_space(1))) void*)(gp), \
    (__attribute__((address_space(3))) void*)(lp), 16, 0, 0)

__device__ __forceinline__ void bar() {
    asm volatile("" ::: "memory");
    __builtin_amdgcn_s_barrier();
    asm volatile("" ::: "memory");
}

// ---------------------------------------------------------------------------
// Bulk f32 -> bf16 conversion (RNE)
// ---------------------------------------------------------------------------
__global__ __launch_bounds__(256) void k_f2b(const float* __restrict__ src,
                                             unsigned short* __restrict__ dst, long n) {
    const long stride = (long)gridDim.x * 256 * 8;
    for (long i = ((long)blockIdx.x * 256 + threadIdx.x) * 8; i < n; i += stride) {
        float4 a = *(const float4*)(src + i);
        float4 b = *(const float4*)(src + i + 4);
        alignas(16) unsigned short t[8] = {f2b(a.x), f2b(a.y), f2b(a.z), f2b(a.w),
                                           f2b(b.x), f2b(b.y), f2b(b.z), f2b(b.w)};
        *(uint4*)(dst + i) = *(const uint4*)t;
    }
}

// ---------------------------------------------------------------------------
// All-layer QKV weight conversion -> wqkv [L][3072][2048] bf16
// ---------------------------------------------------------------------------
__global__ __launch_bounds__(256) void k_f2b_qkv(const float* __restrict__ Wq,
                                                 const float* __restrict__ Wk,
                                                 const float* __restrict__ Wv,
                                                 unsigned short* __restrict__ dst) {
    const long total = (long)NLAYERS * 3072 * 256;   // 8-elem units
    const long stride = (long)gridDim.x * 256;
    for (long u = (long)blockIdx.x * 256 + threadIdx.x; u < total; u += stride) {
        long l = u / (3072 * 256);
        long rem = u - l * (3072 * 256);
        long row = rem >> 8, cv = rem & 255;
        const float* src;
        if (row < 2048)      src = Wq + ((l * 2048 + row) << 11) + (cv << 3);
        else if (row < 2560) src = Wk + ((l * 512 + row - 2048) << 11) + (cv << 3);
        else                 src = Wv + ((l * 512 + row - 2560) << 11) + (cv << 3);
        float4 a = *(const float4*)src;
        float4 b = *(const float4*)(src + 4);
        alignas(16) unsigned short t[8] = {f2b(a.x), f2b(a.y), f2b(a.z), f2b(a.w),
                                           f2b(b.x), f2b(b.y), f2b(b.z), f2b(b.w)};
        *(uint4*)(dst + (u << 3)) = *(const uint4*)t;
    }
}

// ---------------------------------------------------------------------------
// All-layer gate/up interleaved conversion -> wgu [L][2*FDIM][2048]
// ---------------------------------------------------------------------------
__global__ __launch_bounds__(256) void k_f2b_gu(const float* __restrict__ Wg,
                                                const float* __restrict__ Wu,
                                                unsigned short* __restrict__ dst) {
    const long total = (long)NLAYERS * 16384 * 256;
    const long stride = (long)gridDim.x * 256;
    for (long u = (long)blockIdx.x * 256 + threadIdx.x; u < total; u += stride) {
        long l = u / (16384 * 256);
        long rem = u - l * (16384 * 256);
        long row = rem >> 8, cv = rem & 255;
        long f = row >> 1;
        const float* src = ((row & 1) ? Wu : Wg) + ((l * FDIM + f) << 11) + (cv << 3);
        float4 a = *(const float4*)src;
        float4 b = *(const float4*)(src + 4);
        alignas(16) unsigned short t[8] = {f2b(a.x), f2b(a.y), f2b(a.z), f2b(a.w),
                                           f2b(b.x), f2b(b.y), f2b(b.z), f2b(b.w)};
        *(uint4*)(dst + (u << 3)) = *(const uint4*)t;
    }
}

// ---------------------------------------------------------------------------
// 256x256 bf16 GEMM, 4-phase/K-tile, compile-time K/LDA/LDB, peeled
// branch-free loop, counted vmcnt(6). Split-K via kslice = swz / nt.
// SOFTWARE-PIPELINED ds_reads: phase p's MFMA uses fragments read during
// phase p-1 (phase 0 exposed once per tile). Compiler-managed lgkm waits
// (reads are compiler-visible loads). GLL refills shifted one phase later
// where the read-before-refill region safety requires it.
// MODE: 0 = C=, 2 = silu-gate epilogue -> Cg bf16 (B rows interleaved g/u).
// ---------------------------------------------------------------------------
template <int MODE, int K, int LDA, int LDB>
__global__ __launch_bounds__(512) void k_gemm256(const unsigned short* __restrict__ A,
                                                 const unsigned short* __restrict__ B,
                                                 float* __restrict__ C,
                                                 unsigned short* __restrict__ Cg,
                                                 int ldc, int mtiles, int nt,
                                                 long cstride) {
    constexpr int nK = K / 64;
    static_assert(nK >= 4 && (nK & 1) == 0, "nK must be even >= 4");
    __shared__ unsigned short As[2][2][128 * 64];   // [buf][half][row*64+col]
    __shared__ unsigned short Bs[2][2][128 * 64];
    const int tid  = threadIdx.x;
    const int lane = tid & 63;
    const int w    = tid >> 6;
    const int wm   = w >> 2, wn = w & 3;            // 2 x 4 wave grid
    const int swz  = xcd_swz(blockIdx.x, gridDim.x);
    const int kslice = swz / nt;
    const int tile   = swz - kslice * nt;
    const int bm   = (tile % mtiles) * 256, bn = (tile / mtiles) * 256;
    const int r16  = lane & 15;
    const int l4   = lane >> 4;
    const int sw   = r16 & 7;

    const int srow = lane >> 3;
    const int scol = ((lane & 7) ^ srow) * 8;
    const unsigned short* Abase = A + (size_t)kslice * K
                                + (size_t)(bm + w * 16 + srow) * LDA + scol;
    const unsigned short* Bbase = B + (size_t)kslice * K
                                + (size_t)(bn + w * 16 + srow) * LDB + scol;

#define STG_A(bb, hh, kk) do { \
    GLL(Abase + (size_t)(hh) * 128 * LDA + (kk),       &As[(bb)][(hh)][(w * 16) * 64]); \
    GLL(Abase + (size_t)((hh) * 128 + 8) * LDA + (kk), &As[(bb)][(hh)][(w * 16 + 8) * 64]); \
} while (0)
#define STG_B(bb, hh, kk) do { \
    GLL(Bbase + (size_t)(hh) * 128 * LDB + (kk),       &Bs[(bb)][(hh)][(w * 16) * 64]); \
    GLL(Bbase + (size_t)((hh) * 128 + 8) * LDB + (kk), &Bs[(bb)][(hh)][(w * 16 + 8) * 64]); \
} while (0)

    f32x4 acc[8][4] = {};
    const int cb0 = ((0 + l4) ^ sw) * 8;
    const int cb1 = ((4 + l4) ^ sw) * 8;

    STG_A(0, 0, 0); STG_A(0, 1, 0); STG_B(0, 0, 0); STG_B(0, 1, 0);
    STG_B(1, 0, 64); STG_B(1, 1, 64); STG_A(1, 0, 64);
    asm volatile("s_waitcnt vmcnt(6)" ::: "memory");
    bar();

#define BLOAD(b) do { \
    const unsigned short* _Bh = Bs[b][wn >> 1]; \
    _Pragma("unroll") \
    for (int _n = 0; _n < 4; _n++) { \
        bq[_n][0] = *(const bf16x8*)&_Bh[((wn & 1) * 64 + _n * 16 + r16) * 64 + cb0]; \
        bq[_n][1] = *(const bf16x8*)&_Bh[((wn & 1) * 64 + _n * 16 + r16) * 64 + cb1]; \
    } \
} while (0)

#define AREAD(bb, p, d0, d1, d2, d3) do { \
    constexpr int _m0 = 2 * (p), _m1 = _m0 + 1; \
    const unsigned short* _Ah = As[bb][_m0 >> 2]; \
    d0 = *(const bf16x8*)&_Ah[(wm * 16 + (_m0 & 3) * 32 + r16) * 64 + cb0]; \
    d1 = *(const bf16x8*)&_Ah[(wm * 16 + (_m0 & 3) * 32 + r16) * 64 + cb1]; \
    d2 = *(const bf16x8*)&_Ah[(wm * 16 + (_m1 & 3) * 32 + r16) * 64 + cb0]; \
    d3 = *(const bf16x8*)&_Ah[(wm * 16 + (_m1 & 3) * 32 + r16) * 64 + cb1]; \
} while (0)

// ks-outer MFMA order; per-acc operand order (ks0 then ks1) preserved.
#define MFMAP(p, s0, s1, s2, s3) do { \
    constexpr int _m0 = 2 * (p), _m1 = _m0 + 1; \
    __builtin_amdgcn_s_setprio(1); \
    _Pragma("unroll") \
    for (int _n = 0; _n < 4; _n++) { \
        acc[_m0][_n] = __builtin_amdgcn_mfma_f32_16x16x32_bf16(s0, bq[_n][0], acc[_m0][_n], 0, 0, 0); \
        acc[_m1][_n] = __builtin_amdgcn_mfma_f32_16x16x32_bf16(s2, bq[_n][0], acc[_m1][_n], 0, 0, 0); \
    } \
    _Pragma("unroll") \
    for (int _n = 0; _n < 4; _n++) { \
        acc[_m0][_n] = __builtin_amdgcn_mfma_f32_16x16x32_bf16(s1, bq[_n][1], acc[_m0][_n], 0, 0, 0); \
        acc[_m1][_n] = __builtin_amdgcn_mfma_f32_16x16x32_bf16(s3, bq[_n][1], acc[_m1][_n], 0, 0, 0); \
    } \
    __builtin_amdgcn_s_setprio(0); \
} while (0)

#define TILE_STEADY(b, t) do { \
    bf16x8 bq[4][2], x0, x1, x2, x3, y0, y1, y2, y3; \
    AREAD(b, 0, x0, x1, x2, x3); \
    BLOAD(b); \
    AREAD(b, 1, y0, y1, y2, y3); \
    STG_A((b) ^ 1, 1, ((t) + 1) * 64); \
    bar(); \
    MFMAP(0, x0, x1, x2, x3); \
    AREAD(b, 2, x0, x1, x2, x3); \
    bar(); \
    MFMAP(1, y0, y1, y2, y3); \
    AREAD(b, 3, y0, y1, y2, y3); \
    STG_B(b, 0, ((t) + 2) * 64); \
    bar(); \
    MFMAP(2, x0, x1, x2, x3); \
    STG_B(b, 1, ((t) + 2) * 64); \
    STG_A(b, 0, ((t) + 2) * 64); \
    bar(); \
    MFMAP(3, y0, y1, y2, y3); \
    asm volatile("s_waitcnt vmcnt(6)" ::: "memory"); \
    bar(); \
} while (0)

#define TILE_2NDLAST(b, t) do { \
    bf16x8 bq[4][2], x0, x1, x2, x3, y0, y1, y2, y3; \
    AREAD(b, 0, x0, x1, x2, x3); \
    BLOAD(b); \
    AREAD(b, 1, y0, y1, y2, y3); \
    STG_A((b) ^ 1, 1, ((t) + 1) * 64); \
    bar(); \
    MFMAP(0, x0, x1, x2, x3); \
    AREAD(b, 2, x0, x1, x2, x3); \
    bar(); \
    MFMAP(1, y0, y1, y2, y3); \
    AREAD(b, 3, y0, y1, y2, y3); \
    bar(); \
    MFMAP(2, x0, x1, x2, x3); \
    bar(); \
    MFMAP(3, y0, y1, y2, y3); \
    asm volatile("s_waitcnt vmcnt(0)" ::: "memory"); \
    bar(); \
} while (0)

#define TILE_LAST(b) do { \
    bf16x8 bq[4][2], x0, x1, x2, x3, y0, y1, y2, y3; \
    AREAD(b, 0, x0, x1, x2, x3); \
    BLOAD(b); \
    AREAD(b, 1, y0, y1, y2, y3); \
    bar(); \
    MFMAP(0, x0, x1, x2, x3); \
    AREAD(b, 2, x0, x1, x2, x3); \
    bar(); \
    MFMAP(1, y0, y1, y2, y3); \
    AREAD(b, 3, y0, y1, y2, y3); \
    bar(); \
    MFMAP(2, x0, x1, x2, x3); \
    bar(); \
    MFMAP(3, y0, y1, y2, y3); \
} while (0)

    for (int t = 0; t < nK - 2; t += 2) {
        TILE_STEADY(0, t);
        TILE_STEADY(1, t + 1);
    }
    TILE_2NDLAST(0, nK - 2);
    TILE_LAST(1);

#undef TILE_STEADY
#undef TILE_2NDLAST
#undef TILE_LAST
#undef MFMAP
#undef AREAD
#undef BLOAD
#undef STG_A
#undef STG_B

    if (MODE == 0) C += (size_t)kslice * cstride;
    const int r0 = l4 * 4;
#pragma unroll
    for (int m = 0; m < 8; m++)
#pragma unroll
        for (int n = 0; n < 4; n++)
#pragma unroll
            for (int j = 0; j < 4; j++) {
                int row = bm + wm * 16 + m * 32 + r0 + j;
                int col = bn + wn * 64 + n * 16 + r16;
                if (MODE == 0) {
                    C[(size_t)row * ldc + col] = acc[m][n][j];
                } else {
                    float v0 = acc[m][n][j];
                    float v1 = __shfl_xor(v0, 1, 64);
                    if (!(r16 & 1)) {
                        float val = v0 / (1.f + __expf(-v0)) * v1;
                        Cg[(size_t)row * ldc + (col >> 1)] = f2b(val);
                    }
                }
            }
}

// ---------------------------------------------------------------------------
// Fused split-K reduce + residual + RMSNorm
// ---------------------------------------------------------------------------
__device__ __forceinline__ float rms_scale(float4 a, float4 b, int tid) {
    float sum = a.x*a.x + a.y*a.y + a.z*a.z + a.w*a.w
              + b.x*b.x + b.y*b.y + b.z*b.z + b.w*b.w;
#pragma unroll
    for (int off = 32; off; off >>= 1) sum += __shfl_xor(sum, off, 64);
    __shared__ float red[4];
    if ((tid & 63) == 0) red[tid >> 6] = sum;
    __syncthreads();
    float tot = red[0] + red[1] + red[2] + red[3];
    return rsqrtf(tot * (1.0f / HDIM) + 1e-5f);
}

__global__ __launch_bounds__(256) void k_rms_radd(unsigned short* __restrict__ out,
                                                  float* __restrict__ h,
                                                  const float* __restrict__ P, long n,
                                                  const float* __restrict__ w) {
    const int s = blockIdx.x, tid = threadIdx.x;
    const size_t base = (size_t)s * HDIM + tid * 8;
    float4 a = *(const float4*)(h + base);
    float4 b = *(const float4*)(h + base + 4);
#pragma unroll
    for (int k = 0; k < 4; k++) {
        const float* p = P + (size_t)k * n + base;
        float4 x = *(const float4*)p;
        float4 y = *(const float4*)(p + 4);
        a.x += x.x; a.y += x.y; a.z += x.z; a.w += x.w;
        b.x += y.x; b.y += y.y; b.z += y.z; b.w += y.w;
    }
    *(float4*)(h + base) = a;
    *(float4*)(h + base + 4) = b;
    float r = rms_scale(a, b, tid);
    const float4* wv = (const float4*)w;
    float4 wa = wv[tid*2], wb = wv[tid*2+1];
    alignas(16) unsigned short t[8];
    t[0] = f2b(a.x*r*wa.x); t[1] = f2b(a.y*r*wa.y);
    t[2] = f2b(a.z*r*wa.z); t[3] = f2b(a.w*r*wa.w);
    t[4] = f2b(b.x*r*wb.x); t[5] = f2b(b.y*r*wb.y);
    t[6] = f2b(b.z*r*wb.z); t[7] = f2b(b.w*r*wb.w);
    *(uint4*)(out + base) = *(const uint4*)t;
}

__global__ __launch_bounds__(256) void k_rmsnorm_bf(unsigned short* __restrict__ out,
                                                    const float* __restrict__ in,
                                                    const float* __restrict__ w) {
    const int s = blockIdx.x, tid = threadIdx.x;
    const float4* x = (const float4*)(in + (size_t)s * HDIM);
    float4 a = x[tid*2], b = x[tid*2+1];
    float r = rms_scale(a, b, tid);
    const float4* wv = (const float4*)w;
    float4 wa = wv[tid*2], wb = wv[tid*2+1];
    alignas(16) unsigned short t[8];
    t[0] = f2b(a.x*r*wa.x); t[1] = f2b(a.y*r*wa.y);
    t[2] = f2b(a.z*r*wa.z); t[3] = f2b(a.w*r*wa.w);
    t[4] = f2b(b.x*r*wb.x); t[5] = f2b(b.y*r*wb.y);
    t[6] = f2b(b.z*r*wb.z); t[7] = f2b(b.w*r*wb.w);
    *(uint4*)(out + (size_t)s * HDIM + tid * 8) = *(const uint4*)t;
}

__global__ __launch_bounds__(256) void k_rmsnorm_f32(float* __restrict__ out,
                                                     const float* __restrict__ in,
                                                     const float* __restrict__ w) {
    const int s = blockIdx.x, tid = threadIdx.x;
    const float4* x = (const float4*)(in + (size_t)s * HDIM);
    float4 a = x[tid*2], b = x[tid*2+1];
    float r = rms_scale(a, b, tid);
    const float4* wv = (const float4*)w;
    float4 wa = wv[tid*2], wb = wv[tid*2+1];
    float4* o = (float4*)(out + (size_t)s * HDIM);
    float4 oa, ob;
    oa.x = a.x*r*wa.x; oa.y = a.y*r*wa.y; oa.z = a.z*r*wa.z; oa.w = a.w*r*wa.w;
    ob.x = b.x*r*wb.x; ob.y = b.y*r*wb.y; ob.z = b.z*r*wb.z; ob.w = b.w*r*wb.w;
    o[tid*2] = oa; o[tid*2+1] = ob;
}

// ---------------------------------------------------------------------------
// bf16 GEMM 128x128 (m97 structure) — fallback #2 path
// ---------------------------------------------------------------------------
template <bool ACCUM>
__global__ __launch_bounds__(256) void k_gemm_bf(const unsigned short* __restrict__ A,
                                                 const unsigned short* __restrict__ B,
                                                 float* __restrict__ C,
                                                 int K, int lda, int ldb, int ldc,
                                                 int mtiles) {
    __shared__ unsigned short As[128 * 32];
    __shared__ unsigned short Bs[128 * 32];
    const int tid  = threadIdx.x;
    const int lane = tid & 63;
    const int w    = tid >> 6;
    const int wm   = w >> 1, wn = w & 1;
    const int bid  = xcd_swz(blockIdx.x, gridDim.x);
    const int bm   = (bid % mtiles) * 128, bn = (bid / mtiles) * 128;
    const int r16  = lane & 15;
    const int l4   = lane >> 4;

    const unsigned short* Ag = A + (size_t)(bm + w * 32 + (lane >> 2)) * lda + (lane & 3) * 8;
    const unsigned short* Bg = B + (size_t)(bn + w * 32 + (lane >> 2)) * ldb + (lane & 3) * 8;
    unsigned short* Al = As + w * 1024;
    unsigned short* Bl = Bs + w * 1024;

    f32x4 acc[4][4] = {};

    for (int k0 = 0; k0 < K; k0 += 32) {
        GLL(Ag + k0,                    Al);
        GLL(Ag + k0 + (size_t)16 * lda, Al + 512);
        GLL(Bg + k0,                    Bl);
        GLL(Bg + k0 + (size_t)16 * ldb, Bl + 512);
        __syncthreads();

        bf16x8 af[4], bf[4];
#pragma unroll
        for (int m = 0; m < 4; m++) af[m] = *(const bf16x8*)&As[(wm * 64 + m * 16 + r16) * 32 + l4 * 8];
#pragma unroll
        for (int n = 0; n < 4; n++) bf[n] = *(const bf16x8*)&Bs[(wn * 64 + n * 16 + r16) * 32 + l4 * 8];
#pragma unroll
        for (int m = 0; m < 4; m++)
#pragma unroll
            for (int n = 0; n < 4; n++)
                acc[m][n] = __builtin_amdgcn_mfma_f32_16x16x32_bf16(af[m], bf[n], acc[m][n], 0, 0, 0);
        __syncthreads();
    }

    const int r0 = l4 * 4;
#pragma unroll
    for (int m = 0; m < 4; m++)
#pragma unroll
        for (int n = 0; n < 4; n++)
#pragma unroll
            for (int j = 0; j < 4; j++) {
                int row = bm + wm * 64 + m * 16 + r0 + j;
                int col = bn + wn * 64 + n * 16 + r16;
                size_t idx = (size_t)row * ldc + col;
                if (ACCUM) C[idx] += acc[m][n][j];
                else       C[idx] = acc[m][n][j];
            }
}

// ---------------------------------------------------------------------------
// f32 GEMM (fallback #3)
// ---------------------------------------------------------------------------
template <bool ACCUM>
__global__ __launch_bounds__(256) void k_gemm(const float* __restrict__ A,
                                              const float* __restrict__ B,
                                              float* __restrict__ C,
                                              int K, int lda, int ldb, int ldc) {
    __shared__ unsigned short As[128][40];
    __shared__ unsigned short Bs[128][40];
    const int tid  = threadIdx.x;
    const int lane = tid & 63;
    const int wid  = tid >> 6;
    const int wm   = wid >> 1, wn = wid & 1;
    const int bm   = blockIdx.y * 128, bn = blockIdx.x * 128;
    const int arow = tid >> 1, ahalf = tid & 1;
    const float* Ab = A + (size_t)(bm + arow) * lda + ahalf * 16;
    const float* Bb = B + (size_t)(bn + arow) * ldb + ahalf * 16;
    const int r16 = lane & 15;
    const int kk  = (lane >> 4) * 8;

    f32x4 acc[4][4] = {};

    for (int k0 = 0; k0 < K; k0 += 32) {
        alignas(16) unsigned short ta[16], tb[16];
#pragma unroll
        for (int i = 0; i < 4; i++) {
            float4 av = *(const float4*)(Ab + k0 + i * 4);
            float4 bv = *(const float4*)(Bb + k0 + i * 4);
            ta[i*4+0] = f2b(av.x); ta[i*4+1] = f2b(av.y);
            ta[i*4+2] = f2b(av.z); ta[i*4+3] = f2b(av.w);
            tb[i*4+0] = f2b(bv.x); tb[i*4+1] = f2b(bv.y);
            tb[i*4+2] = f2b(bv.z); tb[i*4+3] = f2b(bv.w);
        }
        __syncthreads();
        *(uint4*)&As[arow][ahalf*16]     = *(const uint4*)&ta[0];
        *(uint4*)&As[arow][ahalf*16 + 8] = *(const uint4*)&ta[8];
        *(uint4*)&Bs[arow][ahalf*16]     = *(const uint4*)&tb[0];
        *(uint4*)&Bs[arow][ahalf*16 + 8] = *(const uint4*)&tb[8];
        __syncthreads();

        bf16x8 af[4], bf[4];
#pragma unroll
        for (int m = 0; m < 4; m++) af[m] = *(const bf16x8*)&As[wm*64 + m*16 + r16][kk];
#pragma unroll
        for (int n = 0; n < 4; n++) bf[n] = *(const bf16x8*)&Bs[wn*64 + n*16 + r16][kk];
#pragma unroll
        for (int m = 0; m < 4; m++)
#pragma unroll
            for (int n = 0; n < 4; n++)
                acc[m][n] = __builtin_amdgcn_mfma_f32_16x16x32_bf16(af[m], bf[n], acc[m][n], 0, 0, 0);
    }

    const int r0 = (lane >> 4) * 4;
#pragma unroll
    for (int m = 0; m < 4; m++)
#pragma unroll
        for (int n = 0; n < 4; n++)
#pragma unroll
            for (int j = 0; j < 4; j++) {
                int row = bm + wm*64 + m*16 + r0 + j;
                int col = bn + wn*64 + n*16 + r16;
                size_t idx = (size_t)row * ldc + col;
                if (ACCUM) C[idx] += acc[m][n][j];
                else       C[idx] = acc[m][n][j];
            }
}

// ---------------------------------------------------------------------------
// Embedding gather
// ---------------------------------------------------------------------------
__global__ __launch_bounds__(256) void k_gather(const int* __restrict__ ids,
                                                const float* __restrict__ embed,
                                                float* __restrict__ h) {
    const int s = blockIdx.x, tid = threadIdx.x;
    const int row = ids[s];
    const float4* src = (const float4*)(embed + (size_t)row * HDIM);
    float4* dst = (float4*)(h + (size_t)s * HDIM);
    dst[tid]       = src[tid];
    dst[tid + 256] = src[tid + 256];
}

// ---------------------------------------------------------------------------
// Q rope -> bf16 (x0.125). Input = P0 (+ P1 if TWO), both [S][3072] f32.
// ---------------------------------------------------------------------------
template <bool TWO>
__global__ __launch_bounds__(256) void k_ropeq(const float* __restrict__ P0,
                                               const float* __restrict__ P1,
                                               unsigned short* __restrict__ q_bf) {
    const int s = blockIdx.x, tid = threadIdx.x;
    for (int idx = tid; idx < 1024; idx += 256) {
        int hh = idx >> 5, j = idx & 31;
        float invf = exp2f(-(float)j * (18.931568569324174f / 32.0f));
        float ang = (float)s * invf;
        float sn, cs;
        __sincosf(ang, &sn, &cs);
        size_t off = (size_t)s * 3072 + hh * 64 + j;
        float xe = P0[off]      + (TWO ? P1[off]      : 0.f);
        float xo = P0[off + 32] + (TWO ? P1[off + 32] : 0.f);
        unsigned short* o = q_bf + (size_t)s * HDIM + hh * 64 + j;
        o[0]  = f2b((xe * cs - xo * sn) * 0.125f);
        o[32] = f2b((xo * cs + xe * sn) * 0.125f);
    }
}

// ---------------------------------------------------------------------------
// K rope -> kbf [kvh][s][64] bf16, 16B-block XOR-swizzled within each row
// (blk ^= s&7); V -> vtb [kvh][64][S] bf16, blocks swizzled per 64-key group
// (blk ^= d&7). Consumed by k_attn2 via global_load_lds (linear LDS dest)
// with the same involution applied on ds_read.
// ---------------------------------------------------------------------------
template <bool TWO>
__global__ __launch_bounds__(256) void k_prep_kv(const float* __restrict__ P0,
                                                 const float* __restrict__ P1,
                                                 unsigned short* __restrict__ kbf,
                                                 unsigned short* __restrict__ vtb) {
    const int s0 = blockIdx.x * 64, tid = threadIdx.x;
    for (int i = tid; i < 64 * 256; i += 256) {
        int r = i >> 8, idx = i & 255;
        int kvh = idx >> 5, j = idx & 31;
        int s = s0 + r;
        float invf = exp2f(-(float)j * (18.931568569324174f / 32.0f));
        float ang = (float)s * invf;
        float sn, cs;
        __sincosf(ang, &sn, &cs);
        size_t off = (size_t)s * 3072 + 2048 + kvh * 64 + j;
        float xe = P0[off]      + (TWO ? P1[off]      : 0.f);
        float xo = P0[off + 32] + (TWO ? P1[off + 32] : 0.f);
        unsigned short* o = kbf + ((size_t)kvh * SEQ + s) * 64;
        const int sw8 = s & 7;
        const int c1 = j + 32;
        o[((((j  >> 3)) ^ sw8) << 3) | (j  & 7)] = f2b(xe * cs - xo * sn);
        o[((((c1 >> 3)) ^ sw8) << 3) | (c1 & 7)] = f2b(xo * cs + xe * sn);
    }
    __shared__ float Ls[64][65];
    for (int kvh = 0; kvh < KVH; kvh++) {
        __syncthreads();
        {
            int r = tid >> 2, c0 = (tid & 3) * 16;
            size_t off = (size_t)(s0 + r) * 3072 + 2560 + kvh * 64 + c0;
#pragma unroll
            for (int i = 0; i < 16; i += 4) {
                float4 x = *(const float4*)(P0 + off + i);
                if (TWO) {
                    float4 y = *(const float4*)(P1 + off + i);
                    x.x += y.x; x.y += y.y; x.z += y.z; x.w += y.w;
                }
                Ls[r][c0+i] = x.x; Ls[r][c0+i+1] = x.y;
                Ls[r][c0+i+2] = x.z; Ls[r][c0+i+3] = x.w;
            }
        }
        __syncthreads();
        {
            int d = tid >> 2, k0 = (tid & 3) * 16;
            alignas(16) unsigned short tmp[16];
#pragma unroll
            for (int i = 0; i < 16; i++) tmp[i] = f2b(Ls[k0 + i][d]);
            unsigned short* dst = vtb + ((size_t)kvh * 64 + d) * SEQ + s0;
            const int b0 = k0 >> 3, dw = d & 7;
            *(uint4*)(dst + (((b0    ) ^ dw) << 3)) = *(const uint4*)tmp;
            *(uint4*)(dst + (((b0 + 1) ^ dw) << 3)) = *(const uint4*)(tmp + 8);
        }
    }
}

// ---------------------------------------------------------------------------
// MFMA flash attention, KVBLK=128, fixed-max softmax, deferred row-sum
// reduce. K/V staged via global_load_lds from pre-swizzled kbf/vtb.
// ---------------------------------------------------------------------------
__global__ __launch_bounds__(256) void k_attn2(const unsigned short* __restrict__ q_bf,
                                               const unsigned short* __restrict__ kbf,
                                               const unsigned short* __restrict__ vtb,
                                               unsigned short* __restrict__ aob) {
    const int hh  = blockIdx.y;
    const int qt  = gridDim.x - 1 - blockIdx.x;   // heavy q-tiles first
    const int qb  = qt * 64;
    const int kvh = hh >> 2;
    const int tid = threadIdx.x, w = tid >> 6, lane = tid & 63;
    const int r16 = lane & 15;
    const int l4  = lane >> 4;
    const int sw  = r16 & 7;
    const int cb0 = ((0 + l4) ^ sw) * 8;
    const int cb1 = ((4 + l4) ^ sw) * 8;

    __shared__ unsigned short Ks[2][64 * 64];
    __shared__ unsigned short Vs[2][64 * 64];
    __shared__ unsigned short Ps[64][72];

    bf16x8 qf[2];
    {
        const unsigned short* qrow = q_bf + (size_t)(qb + w*16 + r16) * HDIM + hh * 64;
        qf[0] = *(const bf16x8*)(qrow + l4 * 8);
        qf[1] = *(const bf16x8*)(qrow + 32 + l4 * 8);
    }

    float l[4] = {0.f, 0.f, 0.f, 0.f};
    f32x4 out[4] = {};
    const int ntiles = qt + 1;

    for (int t0 = 0; t0 < ntiles; t0 += 2) {
        const bool two = (t0 + 1 < ntiles);
        __syncthreads();   // prev iteration's LDS reads complete
        {
            const unsigned short* ksrc = kbf + ((size_t)kvh * SEQ + t0 * 64 + w * 16) * 64
                                       + (size_t)lane * 8;
            GLL(ksrc,       &Ks[0][(w * 16) * 64]);
            GLL(ksrc + 512, &Ks[0][(w * 16 + 8) * 64]);
            const unsigned short* vsrc = vtb
                + ((size_t)(kvh * 64 + w * 16 + (lane >> 3))) * SEQ
                + t0 * 64 + (lane & 7) * 8;
            GLL(vsrc,           &Vs[0][(w * 16) * 64]);
            GLL(vsrc + 8 * SEQ, &Vs[0][(w * 16 + 8) * 64]);
            if (two) {
                GLL(ksrc + 4096,       &Ks[1][(w * 16) * 64]);
                GLL(ksrc + 4096 + 512, &Ks[1][(w * 16 + 8) * 64]);
                GLL(vsrc + 64,           &Vs[1][(w * 16) * 64]);
                GLL(vsrc + 64 + 8 * SEQ, &Vs[1][(w * 16 + 8) * 64]);
            }
        }
        __syncthreads();   // drains vmcnt -> staged tiles visible

        f32x4 s[2][4] = {};
#pragma unroll
        for (int n = 0; n < 4; n++) {
            bf16x8 kf0 = *(const bf16x8*)&Ks[0][(n*16 + r16) * 64 + cb0];
            bf16x8 kf1 = *(const bf16x8*)&Ks[0][(n*16 + r16) * 64 + cb1];
            s[0][n] = __builtin_amdgcn_mfma_f32_16x16x32_bf16(qf[0], kf0, s[0][n], 0, 0, 0);
            s[0][n] = __builtin_amdgcn_mfma_f32_16x16x32_bf16(qf[1], kf1, s[0][n], 0, 0, 0);
        }
        if (two) {
#pragma unroll
            for (int n = 0; n < 4; n++) {
                bf16x8 kf0 = *(const bf16x8*)&Ks[1][(n*16 + r16) * 64 + cb0];
                bf16x8 kf1 = *(const bf16x8*)&Ks[1][(n*16 + r16) * 64 + cb1];
                s[1][n] = __builtin_amdgcn_mfma_f32_16x16x32_bf16(qf[0], kf0, s[1][n], 0, 0, 0);
                s[1][n] = __builtin_amdgcn_mfma_f32_16x16x32_bf16(qf[1], kf1, s[1][n], 0, 0, 0);
            }
        }

        const int dh = qt - t0;     // diagonal half index if < 2
        if (dh < 2) {
#pragma unroll
            for (int n = 0; n < 4; n++)
#pragma unroll
                for (int j = 0; j < 4; j++) {
                    int qrow = w*16 + l4*4 + j;
                    int key  = n*16 + r16;
                    if (key > qrow) { if (dh == 0) s[0][n][j] = -1e30f; else s[1][n][j] = -1e30f; }
                }
        }

        // fixed-max exp + per-lane partial row sums (reduce deferred to end)
#pragma unroll
        for (int j = 0; j < 4; j++) {
            float rp = 0.f;
#pragma unroll
            for (int n = 0; n < 4; n++) {
                float p = __expf(s[0][n][j]);
                s[0][n][j] = p;
                rp += p;
            }
            if (two) {
#pragma unroll
                for (int n = 0; n < 4; n++) {
                    float p = __expf(s[1][n][j]);
                    s[1][n][j] = p;
                    rp += p;
                }
            }
            l[j] += rp;
        }

        // half 0: P -> LDS (own rows) -> PV
#pragma unroll
        for (int n = 0; n < 4; n++)
#pragma unroll
            for (int j = 0; j < 4; j++)
                Ps[w*16 + l4*4 + j][n*16 + r16] = f2b(s[0][n][j]);
#pragma unroll
        for (int ks = 0; ks < 2; ks++) {
            bf16x8 pa = *(const bf16x8*)&Ps[w*16 + r16][ks*32 + l4*8];
            const int cb = ks ? cb1 : cb0;
#pragma unroll
            for (int n = 0; n < 4; n++) {
                bf16x8 vf = *(const bf16x8*)&Vs[0][(n*16 + r16) * 64 + cb];
                out[n] = __builtin_amdgcn_mfma_f32_16x16x32_bf16(pa, vf, out[n], 0, 0, 0);
            }
        }
        if (two) {
#pragma unroll
            for (int n = 0; n < 4; n++)
#pragma unroll
                for (int j = 0; j < 4; j++)
                    Ps[w*16 + l4*4 + j][n*16 + r16] = f2b(s[1][n][j]);
#pragma unroll
            for (int ks = 0; ks < 2; ks++) {
                bf16x8 pa = *(const bf16x8*)&Ps[w*16 + r16][ks*32 + l4*8];
                const int cb = ks ? cb1 : cb0;
#pragma unroll
                for (int n = 0; n < 4; n++) {
                    bf16x8 vf = *(const bf16x8*)&Vs[1][(n*16 + r16) * 64 + cb];
                    out[n] = __builtin_amdgcn_mfma_f32_16x16x32_bf16(pa, vf, out[n], 0, 0, 0);
                }
            }
        }
    }

    // deferred row-sum reduce across the 16-lane column group
#pragma unroll
    for (int j = 0; j < 4; j++) {
#pragma unroll
        for (int off = 1; off < 16; off <<= 1) l[j] += __shfl_xor(l[j], off, 64);
    }

#pragma unroll
    for (int n = 0; n < 4; n++)
#pragma unroll
        for (int j = 0; j < 4; j++) {
            int row = qb + w*16 + l4*4 + j;
            int col = hh*64 + n*16 + r16;
            aob[(size_t)row * HDIM + col] = f2b(out[n][j] / l[j]);
        }
}

// ---------------------------------------------------------------------------
// Fallback #3 kernels (f32 path)
// ---------------------------------------------------------------------------
__global__ __launch_bounds__(256) void k_rope(float* __restrict__ x, int nh,
                                              float scale, int ld) {
    const int s = blockIdx.x, tid = threadIdx.x;
    const int total = nh * 32;
    for (int idx = tid; idx < total; idx += 256) {
        int hh = idx >> 5, j = idx & 31;
        float invf = exp2f(-(float)j * (18.931568569324174f / 32.0f));
        float ang = (float)s * invf;
        float sn, cs;
        __sincosf(ang, &sn, &cs);
        float* p = x + (size_t)s * ld + hh * 64 + j;
        float xe = p[0], xo = p[32];
        p[0]  = (xe * cs - xo * sn) * scale;
        p[32] = (xo * cs + xe * sn) * scale;
    }
}

__global__ __launch_bounds__(256) void k_vtrans(const float* __restrict__ v, int ldv,
                                                unsigned short* __restrict__ vt) {
    __shared__ float Ls[64][65];
    const int tid = threadIdx.x;
    const int kb = blockIdx.x * 64, db = blockIdx.y * 64;
    {
        int r = tid >> 2, c0 = (tid & 3) * 16;
        const float* src = v + (size_t)(kb + r) * ldv + db + c0;
#pragma unroll
        for (int i = 0; i < 16; i += 4) {
            float4 x = *(const float4*)(src + i);
            Ls[r][c0+i] = x.x; Ls[r][c0+i+1] = x.y;
            Ls[r][c0+i+2] = x.z; Ls[r][c0+i+3] = x.w;
        }
    }
    __syncthreads();
    {
        int d = tid >> 2, k0 = (tid & 3) * 16;
        alignas(16) unsigned short tmp[16];
#pragma unroll
        for (int i = 0; i < 16; i++) tmp[i] = f2b(Ls[k0 + i][d]);
        unsigned short* dst = vt + (size_t)(db + d) * SEQ + kb + k0;
        *(uint4*)dst       = *(const uint4*)tmp;
        *(uint4*)(dst + 8) = *(const uint4*)(tmp + 8);
    }
}

__global__ __launch_bounds__(256) void k_attn_f32(float* __restrict__ q, int ldq,
                                                  const float* __restrict__ kb, int ldk,
                                                  const unsigned short* __restrict__ vt) {
    const int hh  = blockIdx.y;
    const int qt  = gridDim.x - 1 - blockIdx.x;
    const int qb  = qt * 64;
    const int kvh = hh >> 2;
    const int tid = threadIdx.x, w = tid >> 6, lane = tid & 63;
    const int r16 = lane & 15;
    const int l4  = lane >> 4;

    __shared__ unsigned short Ks[64][72];
    __shared__ unsigned short Vs[64][72];
    __shared__ unsigned short Ps[64][72];

    bf16x8 qf[2];
    {
        const float* qrow = q + (size_t)(qb + w*16 + r16) * ldq + hh * 64;
#pragma unroll
        for (int ks = 0; ks < 2; ks++) {
            alignas(16) unsigned short t[8];
#pragma unroll
            for (int i = 0; i < 8; i += 4) {
                float4 x = *(const float4*)(qrow + ks*32 + l4*8 + i);
                t[i] = f2b(x.x); t[i+1] = f2b(x.y); t[i+2] = f2b(x.z); t[i+3] = f2b(x.w);
            }
            qf[ks] = *(const bf16x8*)t;
        }
    }

    float m[4] = {-1e30f, -1e30f, -1e30f, -1e30f};
    float l[4] = {0.f, 0.f, 0.f, 0.f};
    f32x4 out[4] = {};

    for (int t = 0; t <= qt; t++) {
        __syncthreads();
        {
            int r = tid >> 2, c0 = (tid & 3) * 16;
            const float* src = kb + (size_t)(t*64 + r) * ldk + kvh*64 + c0;
            alignas(16) unsigned short tmp[16];
#pragma unroll
            for (int i = 0; i < 16; i += 4) {
                float4 x = *(const float4*)(src + i);
                tmp[i]   = f2b(x.x); tmp[i+1] = f2b(x.y);
                tmp[i+2] = f2b(x.z); tmp[i+3] = f2b(x.w);
            }
            *(uint4*)&Ks[r][c0]     = *(const uint4*)tmp;
            *(uint4*)&Ks[r][c0 + 8] = *(const uint4*)(tmp + 8);
            const unsigned short* vsrc = vt + (size_t)(kvh*64 + r) * SEQ + t*64 + c0;
            *(uint4*)&Vs[r][c0]     = *(const uint4*)vsrc;
            *(uint4*)&Vs[r][c0 + 8] = *(const uint4*)(vsrc + 8);
        }
        __syncthreads();

        f32x4 s[4] = {};
#pragma unroll
        for (int ks = 0; ks < 2; ks++)
#pragma unroll
            for (int n = 0; n < 4; n++) {
                bf16x8 kf = *(const bf16x8*)&Ks[n*16 + r16][ks*32 + l4*8];
                s[n] = __builtin_amdgcn_mfma_f32_16x16x32_bf16(qf[ks], kf, s[n], 0, 0, 0);
            }

        if (t == qt) {
#pragma unroll
            for (int n = 0; n < 4; n++)
#pragma unroll
                for (int j = 0; j < 4; j++) {
                    int qrow = w*16 + l4*4 + j;
                    int key  = n*16 + r16;
                    if (key > qrow) s[n][j] = -1e30f;
                }
        }

        float corr[4];
#pragma unroll
        for (int j = 0; j < 4; j++) {
            float mx = fmaxf(fmaxf(s[0][j], s[1][j]), fmaxf(s[2][j], s[3][j]));
#pragma unroll
            for (int off = 1; off < 16; off <<= 1) mx = fmaxf(mx, __shfl_xor(mx, off, 64));
            float mn = fmaxf(m[j], mx);
            corr[j] = __expf(m[j] - mn);
            m[j] = mn;
            float rs = 0.f;
#pragma unroll
            for (int n = 0; n < 4; n++) {
                float p = __expf(s[n][j] - mn);
                s[n][j] = p;
                rs += p;
            }
#pragma unroll
            for (int off = 1; off < 16; off <<= 1) rs += __shfl_xor(rs, off, 64);
            l[j] = l[j] * corr[j] + rs;
        }

#pragma unroll
        for (int n = 0; n < 4; n++)
#pragma unroll
            for (int j = 0; j < 4; j++)
                Ps[w*16 + l4*4 + j][n*16 + r16] = f2b(s[n][j]);

#pragma unroll
        for (int n = 0; n < 4; n++)
#pragma unroll
            for (int j = 0; j < 4; j++) out[n][j] *= corr[j];

#pragma unroll
        for (int ks = 0; ks < 2; ks++) {
            bf16x8 pa = *(const bf16x8*)&Ps[w*16 + r16][ks*32 + l4*8];
#pragma unroll
            for (int n = 0; n < 4; n++) {
                bf16x8 vf = *(const bf16x8*)&Vs[n*16 + r16][ks*32 + l4*8];
                out[n] = __builtin_amdgcn_mfma_f32_16x16x32_bf16(pa, vf, out[n], 0, 0, 0);
            }
        }
    }

#pragma unroll
    for (int n = 0; n < 4; n++)
#pragma unroll
        for (int j = 0; j < 4; j++)
            q[(size_t)(qb + w*16 + l4*4 + j) * ldq + hh*64 + n*16 + r16] = out[n][j] / l[j];
}

__global__ __launch_bounds__(256) void k_silu(float* __restrict__ g,
                                              const float* __restrict__ u) {
    const size_t i = (size_t)blockIdx.x * 256 + threadIdx.x;
    float4 gv = ((const float4*)g)[i];
    float4 uv = ((const float4*)u)[i];
    gv.x = gv.x / (1.f + __expf(-gv.x)) * uv.x;
    gv.y = gv.y / (1.f + __expf(-gv.y)) * uv.y;
    gv.z = gv.z / (1.f + __expf(-gv.z)) * uv.z;
    gv.w = gv.w / (1.f + __expf(-gv.w)) * uv.w;
    ((float4*)g)[i] = gv;
}

extern "C" void kernel_launch(void* const* d_in, const int* in_sizes, int n_in,
                              void* d_out, int out_size, void* d_ws, size_t ws_size,
                              hipStream_t stream) {
    (void)in_sizes; (void)n_in; (void)out_size;
    const int*   ids   = (const int*)d_in[0];
    const float* embed = (const float*)d_in[1];
    const float* ln1   = (const float*)d_in[2];
    const float* Wq    = (const float*)d_in[3];
    const float* Wk    = (const float*)d_in[4];
    const float* Wv    = (const float*)d_in[5];
    const float* Wo    = (const float*)d_in[6];
    const float* ln2   = (const float*)d_in[7];
    const float* Wg    = (const float*)d_in[8];
    const float* Wu    = (const float*)d_in[9];
    const float* Wd    = (const float*)d_in[10];
    const float* fln   = (const float*)d_in[11];
    float* out = (float*)d_out;

    char* base = (char*)d_ws;
    size_t off = 0;
    auto alloc = [&](size_t bytes) -> char* {
        char* r = base + off;
        off = (off + bytes + 255) & ~(size_t)255;
        return r;
    };
    float* h     = (float*)alloc((size_t)SEQ * HDIM * 4);
    unsigned short* hn_bf = (unsigned short*)alloc((size_t)SEQ * HDIM * 2);
    unsigned short* aob   = (unsigned short*)alloc((size_t)SEQ * HDIM * 2);
    unsigned short* gated = (unsigned short*)alloc((size_t)SEQ * FDIM * 2);
    unsigned short* q_bf  = (unsigned short*)alloc((size_t)SEQ * HDIM * 2);
    unsigned short* kbf   = (unsigned short*)alloc((size_t)KVH * SEQ * 64 * 2);
    unsigned short* vtb   = (unsigned short*)alloc((size_t)KVH * 64 * SEQ * 2);
    unsigned short* wqkv  = (unsigned short*)alloc((size_t)NLAYERS * 3072 * HDIM * 2);
    unsigned short* wo_b  = (unsigned short*)alloc((size_t)NLAYERS * HDIM * HDIM * 2);
    unsigned short* wgu   = (unsigned short*)alloc((size_t)NLAYERS * 2 * FDIM * HDIM * 2);
    unsigned short* wd_b  = (unsigned short*)alloc((size_t)NLAYERS * HDIM * FDIM * 2);
    unsigned short* emb_b = (unsigned short*)alloc((size_t)VOCAB * HDIM * 2);
    char* Sreg = alloc((size_t)4 * SEQ * HDIM * 4);   // 67 MB: split-K partials
    const size_t REQ_MAIN = off;
    const size_t REQ_FB2  = REQ_MAIN - (size_t)4 * SEQ * HDIM * 4
                          + (((size_t)SEQ * 3072 * 4 + 255) & ~(size_t)255);

    const long LQ = (long)HDIM * HDIM;
    const long LGU = 2L * FDIM * HDIM;
    const long LG = (long)FDIM * HDIM;
    const long MSZ = (long)SEQ * 3072;      // qkv partial slice elems
    const long HSZ = (long)SEQ * HDIM;      // h-sized slice elems

    if (ws_size >= REQ_MAIN) {
        float* Pf = (float*)Sreg;
        // weight conversions (5 launches)
        k_f2b_qkv<<<2048, 256, 0, stream>>>(Wq, Wk, Wv, wqkv);
        k_f2b_gu<<<2048, 256, 0, stream>>>(Wg, Wu, wgu);
        k_f2b<<<2048, 256, 0, stream>>>(Wo, wo_b, (long)NLAYERS * LQ);
        k_f2b<<<2048, 256, 0, stream>>>(Wd, wd_b, (long)NLAYERS * LG);
        k_f2b<<<2048, 256, 0, stream>>>(embed, emb_b, (long)VOCAB * HDIM);

        k_gather<<<SEQ, 256, 0, stream>>>(ids, embed, h);
        k_rmsnorm_bf<<<SEQ, 256, 0, stream>>>(hn_bf, h, ln1);

        for (int i = 0; i < NLAYERS; i++) {
            // QKV: split-K=2, reduce fused into rope/prep
            k_gemm256<0, 1024, 2048, 2048><<<192, 512, 0, stream>>>(
                hn_bf, wqkv + (long)i * 3072 * HDIM, Pf, nullptr, 3072, 8, 96, MSZ);
            k_ropeq<true><<<SEQ, 256, 0, stream>>>(Pf, Pf + MSZ, q_bf);
            k_prep_kv<true><<<SEQ / 64, 256, 0, stream>>>(Pf, Pf + MSZ, kbf, vtb);
            k_attn2<<<dim3(SEQ / 64, NHEADS), 256, 0, stream>>>(q_bf, kbf, vtb, aob);
            // Wo: split-K=4, then fused h += sum(P) ; hn = rms(h)*ln2
            k_gemm256<0, 512, 2048, 2048><<<256, 512, 0, stream>>>(
                aob, wo_b + (long)i * LQ, Pf, nullptr, 2048, 8, 64, HSZ);
            k_rms_radd<<<SEQ, 256, 0, stream>>>(hn_bf, h, Pf, HSZ, ln2 + i * HDIM);
            // gate+up fused, silu epilogue
            k_gemm256<2, 2048, 2048, 2048><<<512, 512, 0, stream>>>(
                hn_bf, wgu + (long)i * LGU, nullptr, gated, FDIM, 8, 512, 0);
            // Wd: split-K=4, then fused h += sum(P) ; hn = rms(h)*next_ln
            k_gemm256<0, 2048, 8192, 8192><<<256, 512, 0, stream>>>(
                gated, wd_b + (long)i * LG, Pf, nullptr, 2048, 8, 64, HSZ);
            const float* nw = (i + 1 < NLAYERS) ? ln1 + (i + 1) * HDIM : fln;
            k_rms_radd<<<SEQ, 256, 0, stream>>>(hn_bf, h, Pf, HSZ, nw);
        }

        k_gemm256<0, 2048, 2048, 2048><<<1000, 512, 0, stream>>>(
            hn_bf, emb_b, out, nullptr, VOCAB, 8, 1000, 0);
    } else if (ws_size >= REQ_FB2) {
        // ============ fallback #2: r6 flow (no split-K partials) ============
        float* qkv = (float*)Sreg;   // [2048][3072] f32
        k_f2b_qkv<<<2048, 256, 0, stream>>>(Wq, Wk, Wv, wqkv);
        k_f2b_gu<<<2048, 256, 0, stream>>>(Wg, Wu, wgu);
        k_f2b<<<2048, 256, 0, stream>>>(Wo, wo_b, (long)NLAYERS * LQ);
        k_f2b<<<2048, 256, 0, stream>>>(Wd, wd_b, (long)NLAYERS * LG);
        k_f2b<<<2048, 256, 0, stream>>>(embed, emb_b, (long)VOCAB * HDIM);

        k_gather<<<SEQ, 256, 0, stream>>>(ids, embed, h);

        for (int i = 0; i < NLAYERS; i++) {
            k_rmsnorm_bf<<<SEQ, 256, 0, stream>>>(hn_bf, h, ln1 + i * HDIM);
            k_gemm_bf<false><<<16 * 24, 256, 0, stream>>>(hn_bf, wqkv + (long)i*3072*HDIM,
                                                          qkv, HDIM, HDIM, HDIM, 3072, 16);
            k_ropeq<false><<<SEQ, 256, 0, stream>>>(qkv, nullptr, q_bf);
            k_prep_kv<false><<<SEQ / 64, 256, 0, stream>>>(qkv, nullptr, kbf, vtb);
            k_attn2<<<dim3(SEQ / 64, NHEADS), 256, 0, stream>>>(q_bf, kbf, vtb, aob);
            k_gemm_bf<true><<<16 * 16, 256, 0, stream>>>(aob, wo_b + (long)i*LQ, h,
                                                         HDIM, HDIM, HDIM, HDIM, 16);
            k_rmsnorm_bf<<<SEQ, 256, 0, stream>>>(hn_bf, h, ln2 + i * HDIM);
            k_gemm256<2, 2048, 2048, 2048><<<512, 512, 0, stream>>>(
                hn_bf, wgu + (long)i * LGU, nullptr, gated, FDIM, 8, 512, 0);
            k_gemm_bf<true><<<16 * 16, 256, 0, stream>>>(gated, wd_b + (long)i*LG, h,
                                                         FDIM, FDIM, FDIM, HDIM, 16);
        }

        k_rmsnorm_bf<<<SEQ, 256, 0, stream>>>(hn_bf, h, fln);
        k_gemm256<0, 2048, 2048, 2048><<<1000, 512, 0, stream>>>(
            hn_bf, emb_b, out, nullptr, VOCAB, 8, 1000, 0);
    } else {
        // ================== fallback #3: f32 path ===========================
        float* ws = (float*)d_ws;
        const size_t M4 = (size_t)4 * 1024 * 1024;
        const size_t M1 = (size_t)1 * 1024 * 1024;
        float* fh  = ws;
        float* hn  = fh + M4;
        float* q   = hn + M4;
        float* kb  = q  + M4;
        float* vb  = kb + M1;
        float* gb  = vb + M1;
        float* ub  = gb + M4;
        unsigned short* fvt = (unsigned short*)(ub + M4);

        k_gather<<<SEQ, 256, 0, stream>>>(ids, embed, fh);

        for (int i = 0; i < NLAYERS; i++) {
            const float* Wq_i = Wq + (size_t)i * HDIM * HDIM;
            const float* Wk_i = Wk + (size_t)i * 512 * HDIM;
            const float* Wv_i = Wv + (size_t)i * 512 * HDIM;
            const float* Wo_i = Wo + (size_t)i * HDIM * HDIM;
            const float* Wg_i = Wg + (size_t)i * FDIM * HDIM;
            const float* Wu_i = Wu + (size_t)i * FDIM * HDIM;
            const float* Wd_i = Wd + (size_t)i * HDIM * FDIM;

            k_rmsnorm_f32<<<SEQ, 256, 0, stream>>>(hn, fh, ln1 + i * HDIM);
            k_gemm<false><<<dim3(16, 16), 256, 0, stream>>>(hn, Wq_i, q,  HDIM, HDIM, HDIM, HDIM);
            k_gemm<false><<<dim3(4, 16),  256, 0, stream>>>(hn, Wk_i, kb, HDIM, HDIM, HDIM, 512);
            k_gemm<false><<<dim3(4, 16),  256, 0, stream>>>(hn, Wv_i, vb, HDIM, HDIM, HDIM, 512);
            k_rope<<<SEQ, 256, 0, stream>>>(q,  NHEADS, 0.125f, HDIM);
            k_rope<<<SEQ, 256, 0, stream>>>(kb, KVH,    1.0f,  512);
            k_vtrans<<<dim3(SEQ/64, 8), 256, 0, stream>>>(vb, 512, fvt);
            k_attn_f32<<<dim3(SEQ/64, NHEADS), 256, 0, stream>>>(q, HDIM, kb, 512, fvt);
            k_gemm<true><<<dim3(16, 16), 256, 0, stream>>>(q, Wo_i, fh, HDIM, HDIM, HDIM, HDIM);

            k_rmsnorm_f32<<<SEQ, 256, 0, stream>>>(hn, fh, ln2 + i * HDIM);
            for (int fc = 0; fc < 4; fc++) {
                const float* Wg_c = Wg_i + (size_t)fc * 2048 * HDIM;
                const float* Wu_c = Wu_i + (size_t)fc * 2048 * HDIM;
                const float* Wd_c = Wd_i + (size_t)fc * 2048;
                k_gemm<false><<<dim3(16, 16), 256, 0, stream>>>(hn, Wg_c, gb, HDIM, HDIM, HDIM, 2048);
                k_gemm<false><<<dim3(16, 16), 256, 0, stream>>>(hn, Wu_c, ub, HDIM, HDIM, HDIM, 2048);
                k_silu<<<4096, 256, 0, stream>>>(gb, ub);
                k_gemm<true><<<dim3(16, 16), 256, 0, stream>>>(gb, Wd_c, fh, 2048, 2048, FDIM, HDIM);
            }
        }

        k_rmsnorm_f32<<<SEQ, 256, 0, stream>>>(hn, fh, fln);
        k_gemm<false><<<dim3(VOCAB/128, 16), 256, 0, stream>>>(hn, embed, out, HDIM, HDIM, HDIM, VOCAB);
    }
}

// Round 12
// 2250.047 us; speedup vs baseline: 1.0106x; 1.0106x over previous
//
#include <hip/hip_runtime.h>
#include <math.h>

#define HDIM 2048
#define SEQ 2048
#define NHEADS 32
#define KVH 8
#define HEADD 64
#define FDIM 8192
#define NLAYERS 4
#define VOCAB 32000

typedef __attribute__((ext_vector_type(4))) float f32x4;
typedef __attribute__((ext_vector_type(8))) short bf16x8;

__device__ __forceinline__ unsigned short f2b(float f) {
    unsigned int u = __float_as_uint(f);
    u += 0x7fff + ((u >> 16) & 1);   // round-to-nearest-even
    return (unsigned short)(u >> 16);
}

// bijective XCD-aware block swizzle [learn_hip m204]
__device__ __forceinline__ int xcd_swz(int bid, int nwg) {
    int xcd = bid & 7, lin = bid >> 3;
    int q = nwg >> 3, r = nwg & 7;
    return (xcd < r ? xcd * (q + 1) : r * (q + 1) + (xcd - r) * q) + lin;
}

#define GLL(gp, lp) __builtin_amdgcn_global_load_lds( \
    (const __attribute__((address_space(1))) void*)(gp), \
    (__attribute__((address_space(3))) void*)(lp), 16, 0, 0)

__device__ __forceinline__ void bar() {
    asm volatile("" ::: "memory");
    __builtin_amdgcn_s_barrier();
    asm volatile("" ::: "memory");
}

// ---------------------------------------------------------------------------
// Bulk f32 -> bf16 conversion (RNE)
// ---------------------------------------------------------------------------
__global__ __launch_bounds__(256) void k_f2b(const float* __restrict__ src,
                                             unsigned short* __restrict__ dst, long n) {
    const long stride = (long)gridDim.x * 256 * 8;
    for (long i = ((long)blockIdx.x * 256 + threadIdx.x) * 8; i < n; i += stride) {
        float4 a = *(const float4*)(src + i);
        float4 b = *(const float4*)(src + i + 4);
        alignas(16) unsigned short t[8] = {f2b(a.x), f2b(a.y), f2b(a.z), f2b(a.w),
                                           f2b(b.x), f2b(b.y), f2b(b.z), f2b(b.w)};
        *(uint4*)(dst + i) = *(const uint4*)t;
    }
}

// ---------------------------------------------------------------------------
// All-layer QKV weight conversion -> wqkv [L][3072][2048] bf16
// ---------------------------------------------------------------------------
__global__ __launch_bounds__(256) void k_f2b_qkv(const float* __restrict__ Wq,
                                                 const float* __restrict__ Wk,
                                                 const float* __restrict__ Wv,
                                                 unsigned short* __restrict__ dst) {
    const long total = (long)NLAYERS * 3072 * 256;   // 8-elem units
    const long stride = (long)gridDim.x * 256;
    for (long u = (long)blockIdx.x * 256 + threadIdx.x; u < total; u += stride) {
        long l = u / (3072 * 256);
        long rem = u - l * (3072 * 256);
        long row = rem >> 8, cv = rem & 255;
        const float* src;
        if (row < 2048)      src = Wq + ((l * 2048 + row) << 11) + (cv << 3);
        else if (row < 2560) src = Wk + ((l * 512 + row - 2048) << 11) + (cv << 3);
        else                 src = Wv + ((l * 512 + row - 2560) << 11) + (cv << 3);
        float4 a = *(const float4*)src;
        float4 b = *(const float4*)(src + 4);
        alignas(16) unsigned short t[8] = {f2b(a.x), f2b(a.y), f2b(a.z), f2b(a.w),
                                           f2b(b.x), f2b(b.y), f2b(b.z), f2b(b.w)};
        *(uint4*)(dst + (u << 3)) = *(const uint4*)t;
    }
}

// ---------------------------------------------------------------------------
// All-layer gate/up interleaved conversion -> wgu [L][2*FDIM][2048]
// ---------------------------------------------------------------------------
__global__ __launch_bounds__(256) void k_f2b_gu(const float* __restrict__ Wg,
                                                const float* __restrict__ Wu,
                                                unsigned short* __restrict__ dst) {
    const long total = (long)NLAYERS * 16384 * 256;
    const long stride = (long)gridDim.x * 256;
    for (long u = (long)blockIdx.x * 256 + threadIdx.x; u < total; u += stride) {
        long l = u / (16384 * 256);
        long rem = u - l * (16384 * 256);
        long row = rem >> 8, cv = rem & 255;
        long f = row >> 1;
        const float* src = ((row & 1) ? Wu : Wg) + ((l * FDIM + f) << 11) + (cv << 3);
        float4 a = *(const float4*)src;
        float4 b = *(const float4*)(src + 4);
        alignas(16) unsigned short t[8] = {f2b(a.x), f2b(a.y), f2b(a.z), f2b(a.w),
                                           f2b(b.x), f2b(b.y), f2b(b.z), f2b(b.w)};
        *(uint4*)(dst + (u << 3)) = *(const uint4*)t;
    }
}

// ---------------------------------------------------------------------------
// 256x256 bf16 GEMM, 4-phase/K-tile, compile-time K/LDA/LDB, peeled
// branch-free loop, counted vmcnt(6). Split-K via kslice = swz / nt.
// MFMA ks-outer ordering (dep distance 8, per-acc order preserved ->
// bitwise identical). lgkmcnt(8) early-drain hint in the 12-ds_read phase.
// MODE: 0 = C=, 2 = silu-gate epilogue -> Cg bf16 (B rows interleaved g/u).
// [R10 variant — best measured configuration]
// ---------------------------------------------------------------------------
template <int MODE, int K, int LDA, int LDB>
__global__ __launch_bounds__(512) void k_gemm256(const unsigned short* __restrict__ A,
                                                 const unsigned short* __restrict__ B,
                                                 float* __restrict__ C,
                                                 unsigned short* __restrict__ Cg,
                                                 int ldc, int mtiles, int nt,
                                                 long cstride) {
    constexpr int nK = K / 64;
    static_assert(nK >= 4 && (nK & 1) == 0, "nK must be even >= 4");
    __shared__ unsigned short As[2][2][128 * 64];   // [buf][half][row*64+col]
    __shared__ unsigned short Bs[2][2][128 * 64];
    const int tid  = threadIdx.x;
    const int lane = tid & 63;
    const int w    = tid >> 6;
    const int wm   = w >> 2, wn = w & 3;            // 2 x 4 wave grid
    const int swz  = xcd_swz(blockIdx.x, gridDim.x);
    const int kslice = swz / nt;
    const int tile   = swz - kslice * nt;
    const int bm   = (tile % mtiles) * 256, bn = (tile / mtiles) * 256;
    const int r16  = lane & 15;
    const int l4   = lane >> 4;
    const int sw   = r16 & 7;

    const int srow = lane >> 3;
    const int scol = ((lane & 7) ^ srow) * 8;
    const unsigned short* Abase = A + (size_t)kslice * K
                                + (size_t)(bm + w * 16 + srow) * LDA + scol;
    const unsigned short* Bbase = B + (size_t)kslice * K
                                + (size_t)(bn + w * 16 + srow) * LDB + scol;

#define STG_A(bb, hh, kk) do { \
    GLL(Abase + (size_t)(hh) * 128 * LDA + (kk),       &As[(bb)][(hh)][(w * 16) * 64]); \
    GLL(Abase + (size_t)((hh) * 128 + 8) * LDA + (kk), &As[(bb)][(hh)][(w * 16 + 8) * 64]); \
} while (0)
#define STG_B(bb, hh, kk) do { \
    GLL(Bbase + (size_t)(hh) * 128 * LDB + (kk),       &Bs[(bb)][(hh)][(w * 16) * 64]); \
    GLL(Bbase + (size_t)((hh) * 128 + 8) * LDB + (kk), &Bs[(bb)][(hh)][(w * 16 + 8) * 64]); \
} while (0)

    f32x4 acc[8][4] = {};
    const int cb0 = ((0 + l4) ^ sw) * 8;
    const int cb1 = ((4 + l4) ^ sw) * 8;

    STG_A(0, 0, 0); STG_A(0, 1, 0); STG_B(0, 0, 0); STG_B(0, 1, 0);
    STG_B(1, 0, 64); STG_B(1, 1, 64); STG_A(1, 0, 64);
    asm volatile("s_waitcnt vmcnt(6)" ::: "memory");
    bar();

#define BLOAD(b) do { \
    const unsigned short* _Bh = Bs[b][wn >> 1]; \
    _Pragma("unroll") \
    for (int _n = 0; _n < 4; _n++) { \
        bq[_n][0] = *(const bf16x8*)&_Bh[((wn & 1) * 64 + _n * 16 + r16) * 64 + cb0]; \
        bq[_n][1] = *(const bf16x8*)&_Bh[((wn & 1) * 64 + _n * 16 + r16) * 64 + cb1]; \
    } \
} while (0)

// ks-outer MFMA order: all 8 accs at ks=0, then all 8 at ks=1.
// Per-acc update order (ks0 then ks1) preserved -> bitwise identical.
#define PHASE(b, p, EXTRA, TAIL) do { \
    constexpr int _m0 = 2 * (p), _m1 = _m0 + 1; \
    const unsigned short* _Ah = As[b][_m0 >> 2]; \
    bf16x8 _a00 = *(const bf16x8*)&_Ah[(wm * 16 + (_m0 & 3) * 32 + r16) * 64 + cb0]; \
    bf16x8 _a01 = *(const bf16x8*)&_Ah[(wm * 16 + (_m0 & 3) * 32 + r16) * 64 + cb1]; \
    bf16x8 _a10 = *(const bf16x8*)&_Ah[(wm * 16 + (_m1 & 3) * 32 + r16) * 64 + cb0]; \
    bf16x8 _a11 = *(const bf16x8*)&_Ah[(wm * 16 + (_m1 & 3) * 32 + r16) * 64 + cb1]; \
    EXTRA; \
    bar(); \
    asm volatile("s_waitcnt lgkmcnt(0)" ::: "memory"); \
    __builtin_amdgcn_s_setprio(1); \
    _Pragma("unroll") \
    for (int _n = 0; _n < 4; _n++) { \
        acc[_m0][_n] = __builtin_amdgcn_mfma_f32_16x16x32_bf16(_a00, bq[_n][0], acc[_m0][_n], 0, 0, 0); \
        acc[_m1][_n] = __builtin_amdgcn_mfma_f32_16x16x32_bf16(_a10, bq[_n][0], acc[_m1][_n], 0, 0, 0); \
    } \
    _Pragma("unroll") \
    for (int _n = 0; _n < 4; _n++) { \
        acc[_m0][_n] = __builtin_amdgcn_mfma_f32_16x16x32_bf16(_a01, bq[_n][1], acc[_m0][_n], 0, 0, 0); \
        acc[_m1][_n] = __builtin_amdgcn_mfma_f32_16x16x32_bf16(_a11, bq[_n][1], acc[_m1][_n], 0, 0, 0); \
    } \
    __builtin_amdgcn_s_setprio(0); \
    TAIL; \
    bar(); \
} while (0)

#define TILE_STEADY(b, t) do { \
    bf16x8 bq[4][2]; \
    PHASE(b, 0, { BLOAD(b); STG_A((b) ^ 1, 1, ((t) + 1) * 64); \
                  asm volatile("s_waitcnt lgkmcnt(8)" ::: "memory"); }, ); \
    PHASE(b, 1, STG_B(b, 0, ((t) + 2) * 64), ); \
    PHASE(b, 2, STG_B(b, 1, ((t) + 2) * 64), ); \
    PHASE(b, 3, STG_A(b, 0, ((t) + 2) * 64), \
          asm volatile("s_waitcnt vmcnt(6)" ::: "memory")); \
} while (0)

#define TILE_2NDLAST(b, t) do { \
    bf16x8 bq[4][2]; \
    PHASE(b, 0, { BLOAD(b); STG_A((b) ^ 1, 1, ((t) + 1) * 64); \
                  asm volatile("s_waitcnt lgkmcnt(8)" ::: "memory"); }, ); \
    PHASE(b, 1, , ); \
    PHASE(b, 2, , ); \
    PHASE(b, 3, , asm volatile("s_waitcnt vmcnt(0)" ::: "memory")); \
} while (0)

#define TILE_LAST(b) do { \
    bf16x8 bq[4][2]; \
    PHASE(b, 0, { BLOAD(b); \
                  asm volatile("s_waitcnt lgkmcnt(8)" ::: "memory"); }, ); \
    PHASE(b, 1, , ); \
    PHASE(b, 2, , ); \
    PHASE(b, 3, , ); \
} while (0)

    for (int t = 0; t < nK - 2; t += 2) {
        TILE_STEADY(0, t);
        TILE_STEADY(1, t + 1);
    }
    TILE_2NDLAST(0, nK - 2);
    TILE_LAST(1);

#undef TILE_STEADY
#undef TILE_2NDLAST
#undef TILE_LAST
#undef PHASE
#undef BLOAD
#undef STG_A
#undef STG_B

    if (MODE == 0) C += (size_t)kslice * cstride;
    const int r0 = l4 * 4;
#pragma unroll
    for (int m = 0; m < 8; m++)
#pragma unroll
        for (int n = 0; n < 4; n++)
#pragma unroll
            for (int j = 0; j < 4; j++) {
                int row = bm + wm * 16 + m * 32 + r0 + j;
                int col = bn + wn * 64 + n * 16 + r16;
                if (MODE == 0) {
                    C[(size_t)row * ldc + col] = acc[m][n][j];
                } else {
                    float v0 = acc[m][n][j];
                    float v1 = __shfl_xor(v0, 1, 64);
                    if (!(r16 & 1)) {
                        float val = v0 / (1.f + __expf(-v0)) * v1;
                        Cg[(size_t)row * ldc + (col >> 1)] = f2b(val);
                    }
                }
            }
}

// ---------------------------------------------------------------------------
// Fused split-K reduce + residual + RMSNorm
// ---------------------------------------------------------------------------
__device__ __forceinline__ float rms_scale(float4 a, float4 b, int tid) {
    float sum = a.x*a.x + a.y*a.y + a.z*a.z + a.w*a.w
              + b.x*b.x + b.y*b.y + b.z*b.z + b.w*b.w;
#pragma unroll
    for (int off = 32; off; off >>= 1) sum += __shfl_xor(sum, off, 64);
    __shared__ float red[4];
    if ((tid & 63) == 0) red[tid >> 6] = sum;
    __syncthreads();
    float tot = red[0] + red[1] + red[2] + red[3];
    return rsqrtf(tot * (1.0f / HDIM) + 1e-5f);
}

__global__ __launch_bounds__(256) void k_rms_radd(unsigned short* __restrict__ out,
                                                  float* __restrict__ h,
                                                  const float* __restrict__ P, long n,
                                                  const float* __restrict__ w) {
    const int s = blockIdx.x, tid = threadIdx.x;
    const size_t base = (size_t)s * HDIM + tid * 8;
    float4 a = *(const float4*)(h + base);
    float4 b = *(const float4*)(h + base + 4);
#pragma unroll
    for (int k = 0; k < 4; k++) {
        const float* p = P + (size_t)k * n + base;
        float4 x = *(const float4*)p;
        float4 y = *(const float4*)(p + 4);
        a.x += x.x; a.y += x.y; a.z += x.z; a.w += x.w;
        b.x += y.x; b.y += y.y; b.z += y.z; b.w += y.w;
    }
    *(float4*)(h + base) = a;
    *(float4*)(h + base + 4) = b;
    float r = rms_scale(a, b, tid);
    const float4* wv = (const float4*)w;
    float4 wa = wv[tid*2], wb = wv[tid*2+1];
    alignas(16) unsigned short t[8];
    t[0] = f2b(a.x*r*wa.x); t[1] = f2b(a.y*r*wa.y);
    t[2] = f2b(a.z*r*wa.z); t[3] = f2b(a.w*r*wa.w);
    t[4] = f2b(b.x*r*wb.x); t[5] = f2b(b.y*r*wb.y);
    t[6] = f2b(b.z*r*wb.z); t[7] = f2b(b.w*r*wb.w);
    *(uint4*)(out + base) = *(const uint4*)t;
}

__global__ __launch_bounds__(256) void k_rmsnorm_bf(unsigned short* __restrict__ out,
                                                    const float* __restrict__ in,
                                                    const float* __restrict__ w) {
    const int s = blockIdx.x, tid = threadIdx.x;
    const float4* x = (const float4*)(in + (size_t)s * HDIM);
    float4 a = x[tid*2], b = x[tid*2+1];
    float r = rms_scale(a, b, tid);
    const float4* wv = (const float4*)w;
    float4 wa = wv[tid*2], wb = wv[tid*2+1];
    alignas(16) unsigned short t[8];
    t[0] = f2b(a.x*r*wa.x); t[1] = f2b(a.y*r*wa.y);
    t[2] = f2b(a.z*r*wa.z); t[3] = f2b(a.w*r*wa.w);
    t[4] = f2b(b.x*r*wb.x); t[5] = f2b(b.y*r*wb.y);
    t[6] = f2b(b.z*r*wb.z); t[7] = f2b(b.w*r*wb.w);
    *(uint4*)(out + (size_t)s * HDIM + tid * 8) = *(const uint4*)t;
}

__global__ __launch_bounds__(256) void k_rmsnorm_f32(float* __restrict__ out,
                                                     const float* __restrict__ in,
                                                     const float* __restrict__ w) {
    const int s = blockIdx.x, tid = threadIdx.x;
    const float4* x = (const float4*)(in + (size_t)s * HDIM);
    float4 a = x[tid*2], b = x[tid*2+1];
    float r = rms_scale(a, b, tid);
    const float4* wv = (const float4*)w;
    float4 wa = wv[tid*2], wb = wv[tid*2+1];
    float4* o = (float4*)(out + (size_t)s * HDIM);
    float4 oa, ob;
    oa.x = a.x*r*wa.x; oa.y = a.y*r*wa.y; oa.z = a.z*r*wa.z; oa.w = a.w*r*wa.w;
    ob.x = b.x*r*wb.x; ob.y = b.y*r*wb.y; ob.z = b.z*r*wb.z; ob.w = b.w*r*wb.w;
    o[tid*2] = oa; o[tid*2+1] = ob;
}

// ---------------------------------------------------------------------------
// bf16 GEMM 128x128 (m97 structure) — fallback #2 path
// ---------------------------------------------------------------------------
template <bool ACCUM>
__global__ __launch_bounds__(256) void k_gemm_bf(const unsigned short* __restrict__ A,
                                                 const unsigned short* __restrict__ B,
                                                 float* __restrict__ C,
                                                 int K, int lda, int ldb, int ldc,
                                                 int mtiles) {
    __shared__ unsigned short As[128 * 32];
    __shared__ unsigned short Bs[128 * 32];
    const int tid  = threadIdx.x;
    const int lane = tid & 63;
    const int w    = tid >> 6;
    const int wm   = w >> 1, wn = w & 1;
    const int bid  = xcd_swz(blockIdx.x, gridDim.x);
    const int bm   = (bid % mtiles) * 128, bn = (bid / mtiles) * 128;
    const int r16  = lane & 15;
    const int l4   = lane >> 4;

    const unsigned short* Ag = A + (size_t)(bm + w * 32 + (lane >> 2)) * lda + (lane & 3) * 8;
    const unsigned short* Bg = B + (size_t)(bn + w * 32 + (lane >> 2)) * ldb + (lane & 3) * 8;
    unsigned short* Al = As + w * 1024;
    unsigned short* Bl = Bs + w * 1024;

    f32x4 acc[4][4] = {};

    for (int k0 = 0; k0 < K; k0 += 32) {
        GLL(Ag + k0,                    Al);
        GLL(Ag + k0 + (size_t)16 * lda, Al + 512);
        GLL(Bg + k0,                    Bl);
        GLL(Bg + k0 + (size_t)16 * ldb, Bl + 512);
        __syncthreads();

        bf16x8 af[4], bf[4];
#pragma unroll
        for (int m = 0; m < 4; m++) af[m] = *(const bf16x8*)&As[(wm * 64 + m * 16 + r16) * 32 + l4 * 8];
#pragma unroll
        for (int n = 0; n < 4; n++) bf[n] = *(const bf16x8*)&Bs[(wn * 64 + n * 16 + r16) * 32 + l4 * 8];
#pragma unroll
        for (int m = 0; m < 4; m++)
#pragma unroll
            for (int n = 0; n < 4; n++)
                acc[m][n] = __builtin_amdgcn_mfma_f32_16x16x32_bf16(af[m], bf[n], acc[m][n], 0, 0, 0);
        __syncthreads();
    }

    const int r0 = l4 * 4;
#pragma unroll
    for (int m = 0; m < 4; m++)
#pragma unroll
        for (int n = 0; n < 4; n++)
#pragma unroll
            for (int j = 0; j < 4; j++) {
                int row = bm + wm * 64 + m * 16 + r0 + j;
                int col = bn + wn * 64 + n * 16 + r16;
                size_t idx = (size_t)row * ldc + col;
                if (ACCUM) C[idx] += acc[m][n][j];
                else       C[idx] = acc[m][n][j];
            }
}

// ---------------------------------------------------------------------------
// f32 GEMM (fallback #3)
// ---------------------------------------------------------------------------
template <bool ACCUM>
__global__ __launch_bounds__(256) void k_gemm(const float* __restrict__ A,
                                              const float* __restrict__ B,
                                              float* __restrict__ C,
                                              int K, int lda, int ldb, int ldc) {
    __shared__ unsigned short As[128][40];
    __shared__ unsigned short Bs[128][40];
    const int tid  = threadIdx.x;
    const int lane = tid & 63;
    const int wid  = tid >> 6;
    const int wm   = wid >> 1, wn = wid & 1;
    const int bm   = blockIdx.y * 128, bn = blockIdx.x * 128;
    const int arow = tid >> 1, ahalf = tid & 1;
    const float* Ab = A + (size_t)(bm + arow) * lda + ahalf * 16;
    const float* Bb = B + (size_t)(bn + arow) * ldb + ahalf * 16;
    const int r16 = lane & 15;
    const int kk  = (lane >> 4) * 8;

    f32x4 acc[4][4] = {};

    for (int k0 = 0; k0 < K; k0 += 32) {
        alignas(16) unsigned short ta[16], tb[16];
#pragma unroll
        for (int i = 0; i < 4; i++) {
            float4 av = *(const float4*)(Ab + k0 + i * 4);
            float4 bv = *(const float4*)(Bb + k0 + i * 4);
            ta[i*4+0] = f2b(av.x); ta[i*4+1] = f2b(av.y);
            ta[i*4+2] = f2b(av.z); ta[i*4+3] = f2b(av.w);
            tb[i*4+0] = f2b(bv.x); tb[i*4+1] = f2b(bv.y);
            tb[i*4+2] = f2b(bv.z); tb[i*4+3] = f2b(bv.w);
        }
        __syncthreads();
        *(uint4*)&As[arow][ahalf*16]     = *(const uint4*)&ta[0];
        *(uint4*)&As[arow][ahalf*16 + 8] = *(const uint4*)&ta[8];
        *(uint4*)&Bs[arow][ahalf*16]     = *(const uint4*)&tb[0];
        *(uint4*)&Bs[arow][ahalf*16 + 8] = *(const uint4*)&tb[8];
        __syncthreads();

        bf16x8 af[4], bf[4];
#pragma unroll
        for (int m = 0; m < 4; m++) af[m] = *(const bf16x8*)&As[wm*64 + m*16 + r16][kk];
#pragma unroll
        for (int n = 0; n < 4; n++) bf[n] = *(const bf16x8*)&Bs[wn*64 + n*16 + r16][kk];
#pragma unroll
        for (int m = 0; m < 4; m++)
#pragma unroll
            for (int n = 0; n < 4; n++)
                acc[m][n] = __builtin_amdgcn_mfma_f32_16x16x32_bf16(af[m], bf[n], acc[m][n], 0, 0, 0);
    }

    const int r0 = (lane >> 4) * 4;
#pragma unroll
    for (int m = 0; m < 4; m++)
#pragma unroll
        for (int n = 0; n < 4; n++)
#pragma unroll
            for (int j = 0; j < 4; j++) {
                int row = bm + wm*64 + m*16 + r0 + j;
                int col = bn + wn*64 + n*16 + r16;
                size_t idx = (size_t)row * ldc + col;
                if (ACCUM) C[idx] += acc[m][n][j];
                else       C[idx] = acc[m][n][j];
            }
}

// ---------------------------------------------------------------------------
// Embedding gather
// ---------------------------------------------------------------------------
__global__ __launch_bounds__(256) void k_gather(const int* __restrict__ ids,
                                                const float* __restrict__ embed,
                                                float* __restrict__ h) {
    const int s = blockIdx.x, tid = threadIdx.x;
    const int row = ids[s];
    const float4* src = (const float4*)(embed + (size_t)row * HDIM);
    float4* dst = (float4*)(h + (size_t)s * HDIM);
    dst[tid]       = src[tid];
    dst[tid + 256] = src[tid + 256];
}

// ---------------------------------------------------------------------------
// Q rope -> bf16 (x0.125). Input = P0 (+ P1 if TWO), both [S][3072] f32.
// ---------------------------------------------------------------------------
template <bool TWO>
__global__ __launch_bounds__(256) void k_ropeq(const float* __restrict__ P0,
                                               const float* __restrict__ P1,
                                               unsigned short* __restrict__ q_bf) {
    const int s = blockIdx.x, tid = threadIdx.x;
    for (int idx = tid; idx < 1024; idx += 256) {
        int hh = idx >> 5, j = idx & 31;
        float invf = exp2f(-(float)j * (18.931568569324174f / 32.0f));
        float ang = (float)s * invf;
        float sn, cs;
        __sincosf(ang, &sn, &cs);
        size_t off = (size_t)s * 3072 + hh * 64 + j;
        float xe = P0[off]      + (TWO ? P1[off]      : 0.f);
        float xo = P0[off + 32] + (TWO ? P1[off + 32] : 0.f);
        unsigned short* o = q_bf + (size_t)s * HDIM + hh * 64 + j;
        o[0]  = f2b((xe * cs - xo * sn) * 0.125f);
        o[32] = f2b((xo * cs + xe * sn) * 0.125f);
    }
}

// ---------------------------------------------------------------------------
// K rope -> kbf [kvh][s][64] bf16, 16B-block XOR-swizzled within each row
// (blk ^= s&7); V -> vtb [kvh][64][S] bf16, blocks swizzled per 64-key group
// (blk ^= d&7). Consumed by k_attn2 via global_load_lds (linear LDS dest)
// with the same involution applied on ds_read.
// ---------------------------------------------------------------------------
template <bool TWO>
__global__ __launch_bounds__(256) void k_prep_kv(const float* __restrict__ P0,
                                                 const float* __restrict__ P1,
                                                 unsigned short* __restrict__ kbf,
                                                 unsigned short* __restrict__ vtb) {
    const int s0 = blockIdx.x * 64, tid = threadIdx.x;
    for (int i = tid; i < 64 * 256; i += 256) {
        int r = i >> 8, idx = i & 255;
        int kvh = idx >> 5, j = idx & 31;
        int s = s0 + r;
        float invf = exp2f(-(float)j * (18.931568569324174f / 32.0f));
        float ang = (float)s * invf;
        float sn, cs;
        __sincosf(ang, &sn, &cs);
        size_t off = (size_t)s * 3072 + 2048 + kvh * 64 + j;
        float xe = P0[off]      + (TWO ? P1[off]      : 0.f);
        float xo = P0[off + 32] + (TWO ? P1[off + 32] : 0.f);
        unsigned short* o = kbf + ((size_t)kvh * SEQ + s) * 64;
        const int sw8 = s & 7;
        const int c1 = j + 32;
        o[((((j  >> 3)) ^ sw8) << 3) | (j  & 7)] = f2b(xe * cs - xo * sn);
        o[((((c1 >> 3)) ^ sw8) << 3) | (c1 & 7)] = f2b(xo * cs + xe * sn);
    }
    __shared__ float Ls[64][65];
    for (int kvh = 0; kvh < KVH; kvh++) {
        __syncthreads();
        {
            int r = tid >> 2, c0 = (tid & 3) * 16;
            size_t off = (size_t)(s0 + r) * 3072 + 2560 + kvh * 64 + c0;
#pragma unroll
            for (int i = 0; i < 16; i += 4) {
                float4 x = *(const float4*)(P0 + off + i);
                if (TWO) {
                    float4 y = *(const float4*)(P1 + off + i);
                    x.x += y.x; x.y += y.y; x.z += y.z; x.w += y.w;
                }
                Ls[r][c0+i] = x.x; Ls[r][c0+i+1] = x.y;
                Ls[r][c0+i+2] = x.z; Ls[r][c0+i+3] = x.w;
            }
        }
        __syncthreads();
        {
            int d = tid >> 2, k0 = (tid & 3) * 16;
            alignas(16) unsigned short tmp[16];
#pragma unroll
            for (int i = 0; i < 16; i++) tmp[i] = f2b(Ls[k0 + i][d]);
            unsigned short* dst = vtb + ((size_t)kvh * 64 + d) * SEQ + s0;
            const int b0 = k0 >> 3, dw = d & 7;
            *(uint4*)(dst + (((b0    ) ^ dw) << 3)) = *(const uint4*)tmp;
            *(uint4*)(dst + (((b0 + 1) ^ dw) << 3)) = *(const uint4*)(tmp + 8);
        }
    }
}

// ---------------------------------------------------------------------------
// MFMA flash attention, KVBLK=128, fixed-max softmax, deferred row-sum
// reduce. K/V staged via global_load_lds from pre-swizzled kbf/vtb.
// ---------------------------------------------------------------------------
__global__ __launch_bounds__(256) void k_attn2(const unsigned short* __restrict__ q_bf,
                                               const unsigned short* __restrict__ kbf,
                                               const unsigned short* __restrict__ vtb,
                                               unsigned short* __restrict__ aob) {
    const int hh  = blockIdx.y;
    const int qt  = gridDim.x - 1 - blockIdx.x;   // heavy q-tiles first
    const int qb  = qt * 64;
    const int kvh = hh >> 2;
    const int tid = threadIdx.x, w = tid >> 6, lane = tid & 63;
    const int r16 = lane & 15;
    const int l4  = lane >> 4;
    const int sw  = r16 & 7;
    const int cb0 = ((0 + l4) ^ sw) * 8;
    const int cb1 = ((4 + l4) ^ sw) * 8;

    __shared__ unsigned short Ks[2][64 * 64];
    __shared__ unsigned short Vs[2][64 * 64];
    __shared__ unsigned short Ps[64][72];

    bf16x8 qf[2];
    {
        const unsigned short* qrow = q_bf + (size_t)(qb + w*16 + r16) * HDIM + hh * 64;
        qf[0] = *(const bf16x8*)(qrow + l4 * 8);
        qf[1] = *(const bf16x8*)(qrow + 32 + l4 * 8);
    }

    float l[4] = {0.f, 0.f, 0.f, 0.f};
    f32x4 out[4] = {};
    const int ntiles = qt + 1;

    for (int t0 = 0; t0 < ntiles; t0 += 2) {
        const bool two = (t0 + 1 < ntiles);
        __syncthreads();   // prev iteration's LDS reads complete
        {
            const unsigned short* ksrc = kbf + ((size_t)kvh * SEQ + t0 * 64 + w * 16) * 64
                                       + (size_t)lane * 8;
            GLL(ksrc,       &Ks[0][(w * 16) * 64]);
            GLL(ksrc + 512, &Ks[0][(w * 16 + 8) * 64]);
            const unsigned short* vsrc = vtb
                + ((size_t)(kvh * 64 + w * 16 + (lane >> 3))) * SEQ
                + t0 * 64 + (lane & 7) * 8;
            GLL(vsrc,           &Vs[0][(w * 16) * 64]);
            GLL(vsrc + 8 * SEQ, &Vs[0][(w * 16 + 8) * 64]);
            if (two) {
                GLL(ksrc + 4096,       &Ks[1][(w * 16) * 64]);
                GLL(ksrc + 4096 + 512, &Ks[1][(w * 16 + 8) * 64]);
                GLL(vsrc + 64,           &Vs[1][(w * 16) * 64]);
                GLL(vsrc + 64 + 8 * SEQ, &Vs[1][(w * 16 + 8) * 64]);
            }
        }
        __syncthreads();   // drains vmcnt -> staged tiles visible

        f32x4 s[2][4] = {};
#pragma unroll
        for (int n = 0; n < 4; n++) {
            bf16x8 kf0 = *(const bf16x8*)&Ks[0][(n*16 + r16) * 64 + cb0];
            bf16x8 kf1 = *(const bf16x8*)&Ks[0][(n*16 + r16) * 64 + cb1];
            s[0][n] = __builtin_amdgcn_mfma_f32_16x16x32_bf16(qf[0], kf0, s[0][n], 0, 0, 0);
            s[0][n] = __builtin_amdgcn_mfma_f32_16x16x32_bf16(qf[1], kf1, s[0][n], 0, 0, 0);
        }
        if (two) {
#pragma unroll
            for (int n = 0; n < 4; n++) {
                bf16x8 kf0 = *(const bf16x8*)&Ks[1][(n*16 + r16) * 64 + cb0];
                bf16x8 kf1 = *(const bf16x8*)&Ks[1][(n*16 + r16) * 64 + cb1];
                s[1][n] = __builtin_amdgcn_mfma_f32_16x16x32_bf16(qf[0], kf0, s[1][n], 0, 0, 0);
                s[1][n] = __builtin_amdgcn_mfma_f32_16x16x32_bf16(qf[1], kf1, s[1][n], 0, 0, 0);
            }
        }

        const int dh = qt - t0;     // diagonal half index if < 2
        if (dh < 2) {
#pragma unroll
            for (int n = 0; n < 4; n++)
#pragma unroll
                for (int j = 0; j < 4; j++) {
                    int qrow = w*16 + l4*4 + j;
                    int key  = n*16 + r16;
                    if (key > qrow) { if (dh == 0) s[0][n][j] = -1e30f; else s[1][n][j] = -1e30f; }
                }
        }

        // fixed-max exp + per-lane partial row sums (reduce deferred to end)
#pragma unroll
        for (int j = 0; j < 4; j++) {
            float rp = 0.f;
#pragma unroll
            for (int n = 0; n < 4; n++) {
                float p = __expf(s[0][n][j]);
                s[0][n][j] = p;
                rp += p;
            }
            if (two) {
#pragma unroll
                for (int n = 0; n < 4; n++) {
                    float p = __expf(s[1][n][j]);
                    s[1][n][j] = p;
                    rp += p;
                }
            }
            l[j] += rp;
        }

        // half 0: P -> LDS (own rows) -> PV
#pragma unroll
        for (int n = 0; n < 4; n++)
#pragma unroll
            for (int j = 0; j < 4; j++)
                Ps[w*16 + l4*4 + j][n*16 + r16] = f2b(s[0][n][j]);
#pragma unroll
        for (int ks = 0; ks < 2; ks++) {
            bf16x8 pa = *(const bf16x8*)&Ps[w*16 + r16][ks*32 + l4*8];
            const int cb = ks ? cb1 : cb0;
#pragma unroll
            for (int n = 0; n < 4; n++) {
                bf16x8 vf = *(const bf16x8*)&Vs[0][(n*16 + r16) * 64 + cb];
                out[n] = __builtin_amdgcn_mfma_f32_16x16x32_bf16(pa, vf, out[n], 0, 0, 0);
            }
        }
        if (two) {
#pragma unroll
            for (int n = 0; n < 4; n++)
#pragma unroll
                for (int j = 0; j < 4; j++)
                    Ps[w*16 + l4*4 + j][n*16 + r16] = f2b(s[1][n][j]);
#pragma unroll
            for (int ks = 0; ks < 2; ks++) {
                bf16x8 pa = *(const bf16x8*)&Ps[w*16 + r16][ks*32 + l4*8];
                const int cb = ks ? cb1 : cb0;
#pragma unroll
                for (int n = 0; n < 4; n++) {
                    bf16x8 vf = *(const bf16x8*)&Vs[1][(n*16 + r16) * 64 + cb];
                    out[n] = __builtin_amdgcn_mfma_f32_16x16x32_bf16(pa, vf, out[n], 0, 0, 0);
                }
            }
        }
    }

    // deferred row-sum reduce across the 16-lane column group
#pragma unroll
    for (int j = 0; j < 4; j++) {
#pragma unroll
        for (int off = 1; off < 16; off <<= 1) l[j] += __shfl_xor(l[j], off, 64);
    }

#pragma unroll
    for (int n = 0; n < 4; n++)
#pragma unroll
        for (int j = 0; j < 4; j++) {
            int row = qb + w*16 + l4*4 + j;
            int col = hh*64 + n*16 + r16;
            aob[(size_t)row * HDIM + col] = f2b(out[n][j] / l[j]);
        }
}

// ---------------------------------------------------------------------------
// Fallback #3 kernels (f32 path)
// ---------------------------------------------------------------------------
__global__ __launch_bounds__(256) void k_rope(float* __restrict__ x, int nh,
                                              float scale, int ld) {
    const int s = blockIdx.x, tid = threadIdx.x;
    const int total = nh * 32;
    for (int idx = tid; idx < total; idx += 256) {
        int hh = idx >> 5, j = idx & 31;
        float invf = exp2f(-(float)j * (18.931568569324174f / 32.0f));
        float ang = (float)s * invf;
        float sn, cs;
        __sincosf(ang, &sn, &cs);
        float* p = x + (size_t)s * ld + hh * 64 + j;
        float xe = p[0], xo = p[32];
        p[0]  = (xe * cs - xo * sn) * scale;
        p[32] = (xo * cs + xe * sn) * scale;
    }
}

__global__ __launch_bounds__(256) void k_vtrans(const float* __restrict__ v, int ldv,
                                                unsigned short* __restrict__ vt) {
    __shared__ float Ls[64][65];
    const int tid = threadIdx.x;
    const int kb = blockIdx.x * 64, db = blockIdx.y * 64;
    {
        int r = tid >> 2, c0 = (tid & 3) * 16;
        const float* src = v + (size_t)(kb + r) * ldv + db + c0;
#pragma unroll
        for (int i = 0; i < 16; i += 4) {
            float4 x = *(const float4*)(src + i);
            Ls[r][c0+i] = x.x; Ls[r][c0+i+1] = x.y;
            Ls[r][c0+i+2] = x.z; Ls[r][c0+i+3] = x.w;
        }
    }
    __syncthreads();
    {
        int d = tid >> 2, k0 = (tid & 3) * 16;
        alignas(16) unsigned short tmp[16];
#pragma unroll
        for (int i = 0; i < 16; i++) tmp[i] = f2b(Ls[k0 + i][d]);
        unsigned short* dst = vt + (size_t)(db + d) * SEQ + kb + k0;
        *(uint4*)dst       = *(const uint4*)tmp;
        *(uint4*)(dst + 8) = *(const uint4*)(tmp + 8);
    }
}

__global__ __launch_bounds__(256) void k_attn_f32(float* __restrict__ q, int ldq,
                                                  const float* __restrict__ kb, int ldk,
                                                  const unsigned short* __restrict__ vt) {
    const int hh  = blockIdx.y;
    const int qt  = gridDim.x - 1 - blockIdx.x;
    const int qb  = qt * 64;
    const int kvh = hh >> 2;
    const int tid = threadIdx.x, w = tid >> 6, lane = tid & 63;
    const int r16 = lane & 15;
    const int l4  = lane >> 4;

    __shared__ unsigned short Ks[64][72];
    __shared__ unsigned short Vs[64][72];
    __shared__ unsigned short Ps[64][72];

    bf16x8 qf[2];
    {
        const float* qrow = q + (size_t)(qb + w*16 + r16) * ldq + hh * 64;
#pragma unroll
        for (int ks = 0; ks < 2; ks++) {
            alignas(16) unsigned short t[8];
#pragma unroll
            for (int i = 0; i < 8; i += 4) {
                float4 x = *(const float4*)(qrow + ks*32 + l4*8 + i);
                t[i] = f2b(x.x); t[i+1] = f2b(x.y); t[i+2] = f2b(x.z); t[i+3] = f2b(x.w);
            }
            qf[ks] = *(const bf16x8*)t;
        }
    }

    float m[4] = {-1e30f, -1e30f, -1e30f, -1e30f};
    float l[4] = {0.f, 0.f, 0.f, 0.f};
    f32x4 out[4] = {};

    for (int t = 0; t <= qt; t++) {
        __syncthreads();
        {
            int r = tid >> 2, c0 = (tid & 3) * 16;
            const float* src = kb + (size_t)(t*64 + r) * ldk + kvh*64 + c0;
            alignas(16) unsigned short tmp[16];
#pragma unroll
            for (int i = 0; i < 16; i += 4) {
                float4 x = *(const float4*)(src + i);
                tmp[i]   = f2b(x.x); tmp[i+1] = f2b(x.y);
                tmp[i+2] = f2b(x.z); tmp[i+3] = f2b(x.w);
            }
            *(uint4*)&Ks[r][c0]     = *(const uint4*)tmp;
            *(uint4*)&Ks[r][c0 + 8] = *(const uint4*)(tmp + 8);
            const unsigned short* vsrc = vt + (size_t)(kvh*64 + r) * SEQ + t*64 + c0;
            *(uint4*)&Vs[r][c0]     = *(const uint4*)vsrc;
            *(uint4*)&Vs[r][c0 + 8] = *(const uint4*)(vsrc + 8);
        }
        __syncthreads();

        f32x4 s[4] = {};
#pragma unroll
        for (int ks = 0; ks < 2; ks++)
#pragma unroll
            for (int n = 0; n < 4; n++) {
                bf16x8 kf = *(const bf16x8*)&Ks[n*16 + r16][ks*32 + l4*8];
                s[n] = __builtin_amdgcn_mfma_f32_16x16x32_bf16(qf[ks], kf, s[n], 0, 0, 0);
            }

        if (t == qt) {
#pragma unroll
            for (int n = 0; n < 4; n++)
#pragma unroll
                for (int j = 0; j < 4; j++) {
                    int qrow = w*16 + l4*4 + j;
                    int key  = n*16 + r16;
                    if (key > qrow) s[n][j] = -1e30f;
                }
        }

        float corr[4];
#pragma unroll
        for (int j = 0; j < 4; j++) {
            float mx = fmaxf(fmaxf(s[0][j], s[1][j]), fmaxf(s[2][j], s[3][j]));
#pragma unroll
            for (int off = 1; off < 16; off <<= 1) mx = fmaxf(mx, __shfl_xor(mx, off, 64));
            float mn = fmaxf(m[j], mx);
            corr[j] = __expf(m[j] - mn);
            m[j] = mn;
            float rs = 0.f;
#pragma unroll
            for (int n = 0; n < 4; n++) {
                float p = __expf(s[n][j] - mn);
                s[n][j] = p;
                rs += p;
            }
#pragma unroll
            for (int off = 1; off < 16; off <<= 1) rs += __shfl_xor(rs, off, 64);
            l[j] = l[j] * corr[j] + rs;
        }

#pragma unroll
        for (int n = 0; n < 4; n++)
#pragma unroll
            for (int j = 0; j < 4; j++)
                Ps[w*16 + l4*4 + j][n*16 + r16] = f2b(s[n][j]);

#pragma unroll
        for (int n = 0; n < 4; n++)
#pragma unroll
            for (int j = 0; j < 4; j++) out[n][j] *= corr[j];

#pragma unroll
        for (int ks = 0; ks < 2; ks++) {
            bf16x8 pa = *(const bf16x8*)&Ps[w*16 + r16][ks*32 + l4*8];
#pragma unroll
            for (int n = 0; n < 4; n++) {
                bf16x8 vf = *(const bf16x8*)&Vs[n*16 + r16][ks*32 + l4*8];
                out[n] = __builtin_amdgcn_mfma_f32_16x16x32_bf16(pa, vf, out[n], 0, 0, 0);
            }
        }
    }

#pragma unroll
    for (int n = 0; n < 4; n++)
#pragma unroll
        for (int j = 0; j < 4; j++)
            q[(size_t)(qb + w*16 + l4*4 + j) * ldq + hh*64 + n*16 + r16] = out[n][j] / l[j];
}

__global__ __launch_bounds__(256) void k_silu(float* __restrict__ g,
                                              const float* __restrict__ u) {
    const size_t i = (size_t)blockIdx.x * 256 + threadIdx.x;
    float4 gv = ((const float4*)g)[i];
    float4 uv = ((const float4*)u)[i];
    gv.x = gv.x / (1.f + __expf(-gv.x)) * uv.x;
    gv.y = gv.y / (1.f + __expf(-gv.y)) * uv.y;
    gv.z = gv.z / (1.f + __expf(-gv.z)) * uv.z;
    gv.w = gv.w / (1.f + __expf(-gv.w)) * uv.w;
    ((float4*)g)[i] = gv;
}

extern "C" void kernel_launch(void* const* d_in, const int* in_sizes, int n_in,
                              void* d_out, int out_size, void* d_ws, size_t ws_size,
                              hipStream_t stream) {
    (void)in_sizes; (void)n_in; (void)out_size;
    const int*   ids   = (const int*)d_in[0];
    const float* embed = (const float*)d_in[1];
    const float* ln1   = (const float*)d_in[2];
    const float* Wq    = (const float*)d_in[3];
    const float* Wk    = (const float*)d_in[4];
    const float* Wv    = (const float*)d_in[5];
    const float* Wo    = (const float*)d_in[6];
    const float* ln2   = (const float*)d_in[7];
    const float* Wg    = (const float*)d_in[8];
    const float* Wu    = (const float*)d_in[9];
    const float* Wd    = (const float*)d_in[10];
    const float* fln   = (const float*)d_in[11];
    float* out = (float*)d_out;

    char* base = (char*)d_ws;
    size_t off = 0;
    auto alloc = [&](size_t bytes) -> char* {
        char* r = base + off;
        off = (off + bytes + 255) & ~(size_t)255;
        return r;
    };
    float* h     = (float*)alloc((size_t)SEQ * HDIM * 4);
    unsigned short* hn_bf = (unsigned short*)alloc((size_t)SEQ * HDIM * 2);
    unsigned short* aob   = (unsigned short*)alloc((size_t)SEQ * HDIM * 2);
    unsigned short* gated = (unsigned short*)alloc((size_t)SEQ * FDIM * 2);
    unsigned short* q_bf  = (unsigned short*)alloc((size_t)SEQ * HDIM * 2);
    unsigned short* kbf   = (unsigned short*)alloc((size_t)KVH * SEQ * 64 * 2);
    unsigned short* vtb   = (unsigned short*)alloc((size_t)KVH * 64 * SEQ * 2);
    unsigned short* wqkv  = (unsigned short*)alloc((size_t)NLAYERS * 3072 * HDIM * 2);
    unsigned short* wo_b  = (unsigned short*)alloc((size_t)NLAYERS * HDIM * HDIM * 2);
    unsigned short* wgu   = (unsigned short*)alloc((size_t)NLAYERS * 2 * FDIM * HDIM * 2);
    unsigned short* wd_b  = (unsigned short*)alloc((size_t)NLAYERS * HDIM * FDIM * 2);
    unsigned short* emb_b = (unsigned short*)alloc((size_t)VOCAB * HDIM * 2);
    char* Sreg = alloc((size_t)4 * SEQ * HDIM * 4);   // 67 MB: split-K partials
    const size_t REQ_MAIN = off;
    const size_t REQ_FB2  = REQ_MAIN - (size_t)4 * SEQ * HDIM * 4
                          + (((size_t)SEQ * 3072 * 4 + 255) & ~(size_t)255);

    const long LQ = (long)HDIM * HDIM;
    const long LGU = 2L * FDIM * HDIM;
    const long LG = (long)FDIM * HDIM;
    const long MSZ = (long)SEQ * 3072;      // qkv partial slice elems
    const long HSZ = (long)SEQ * HDIM;      // h-sized slice elems

    if (ws_size >= REQ_MAIN) {
        float* Pf = (float*)Sreg;
        // weight conversions (5 launches)
        k_f2b_qkv<<<2048, 256, 0, stream>>>(Wq, Wk, Wv, wqkv);
        k_f2b_gu<<<2048, 256, 0, stream>>>(Wg, Wu, wgu);
        k_f2b<<<2048, 256, 0, stream>>>(Wo, wo_b, (long)NLAYERS * LQ);
        k_f2b<<<2048, 256, 0, stream>>>(Wd, wd_b, (long)NLAYERS * LG);
        k_f2b<<<2048, 256, 0, stream>>>(embed, emb_b, (long)VOCAB * HDIM);

        k_gather<<<SEQ, 256, 0, stream>>>(ids, embed, h);
        k_rmsnorm_bf<<<SEQ, 256, 0, stream>>>(hn_bf, h, ln1);

        for (int i = 0; i < NLAYERS; i++) {
            // QKV: split-K=2, reduce fused into rope/prep
            k_gemm256<0, 1024, 2048, 2048><<<192, 512, 0, stream>>>(
                hn_bf, wqkv + (long)i * 3072 * HDIM, Pf, nullptr, 3072, 8, 96, MSZ);
            k_ropeq<true><<<SEQ, 256, 0, stream>>>(Pf, Pf + MSZ, q_bf);
            k_prep_kv<true><<<SEQ / 64, 256, 0, stream>>>(Pf, Pf + MSZ, kbf, vtb);
            k_attn2<<<dim3(SEQ / 64, NHEADS), 256, 0, stream>>>(q_bf, kbf, vtb, aob);
            // Wo: split-K=4, then fused h += sum(P) ; hn = rms(h)*ln2
            k_gemm256<0, 512, 2048, 2048><<<256, 512, 0, stream>>>(
                aob, wo_b + (long)i * LQ, Pf, nullptr, 2048, 8, 64, HSZ);
            k_rms_radd<<<SEQ, 256, 0, stream>>>(hn_bf, h, Pf, HSZ, ln2 + i * HDIM);
            // gate+up fused, silu epilogue
            k_gemm256<2, 2048, 2048, 2048><<<512, 512, 0, stream>>>(
                hn_bf, wgu + (long)i * LGU, nullptr, gated, FDIM, 8, 512, 0);
            // Wd: split-K=4, then fused h += sum(P) ; hn = rms(h)*next_ln
            k_gemm256<0, 2048, 8192, 8192><<<256, 512, 0, stream>>>(
                gated, wd_b + (long)i * LG, Pf, nullptr, 2048, 8, 64, HSZ);
            const float* nw = (i + 1 < NLAYERS) ? ln1 + (i + 1) * HDIM : fln;
            k_rms_radd<<<SEQ, 256, 0, stream>>>(hn_bf, h, Pf, HSZ, nw);
        }

        k_gemm256<0, 2048, 2048, 2048><<<1000, 512, 0, stream>>>(
            hn_bf, emb_b, out, nullptr, VOCAB, 8, 1000, 0);
    } else if (ws_size >= REQ_FB2) {
        // ============ fallback #2: r6 flow (no split-K partials) ============
        float* qkv = (float*)Sreg;   // [2048][3072] f32
        k_f2b_qkv<<<2048, 256, 0, stream>>>(Wq, Wk, Wv, wqkv);
        k_f2b_gu<<<2048, 256, 0, stream>>>(Wg, Wu, wgu);
        k_f2b<<<2048, 256, 0, stream>>>(Wo, wo_b, (long)NLAYERS * LQ);
        k_f2b<<<2048, 256, 0, stream>>>(Wd, wd_b, (long)NLAYERS * LG);
        k_f2b<<<2048, 256, 0, stream>>>(embed, emb_b, (long)VOCAB * HDIM);

        k_gather<<<SEQ, 256, 0, stream>>>(ids, embed, h);

        for (int i = 0; i < NLAYERS; i++) {
            k_rmsnorm_bf<<<SEQ, 256, 0, stream>>>(hn_bf, h, ln1 + i * HDIM);
            k_gemm_bf<false><<<16 * 24, 256, 0, stream>>>(hn_bf, wqkv + (long)i*3072*HDIM,
                                                          qkv, HDIM, HDIM, HDIM, 3072, 16);
            k_ropeq<false><<<SEQ, 256, 0, stream>>>(qkv, nullptr, q_bf);
            k_prep_kv<false><<<SEQ / 64, 256, 0, stream>>>(qkv, nullptr, kbf, vtb);
            k_attn2<<<dim3(SEQ / 64, NHEADS), 256, 0, stream>>>(q_bf, kbf, vtb, aob);
            k_gemm_bf<true><<<16 * 16, 256, 0, stream>>>(aob, wo_b + (long)i*LQ, h,
                                                         HDIM, HDIM, HDIM, HDIM, 16);
            k_rmsnorm_bf<<<SEQ, 256, 0, stream>>>(hn_bf, h, ln2 + i * HDIM);
            k_gemm256<2, 2048, 2048, 2048><<<512, 512, 0, stream>>>(
                hn_bf, wgu + (long)i * LGU, nullptr, gated, FDIM, 8, 512, 0);
            k_gemm_bf<true><<<16 * 16, 256, 0, stream>>>(gated, wd_b + (long)i*LG, h,
                                                         FDIM, FDIM, FDIM, HDIM, 16);
        }

        k_rmsnorm_bf<<<SEQ, 256, 0, stream>>>(hn_bf, h, fln);
        k_gemm256<0, 2048, 2048, 2048><<<1000, 512, 0, stream>>>(
            hn_bf, emb_b, out, nullptr, VOCAB, 8, 1000, 0);
    } else {
        // ================== fallback #3: f32 path ===========================
        float* ws = (float*)d_ws;
        const size_t M4 = (size_t)4 * 1024 * 1024;
        const size_t M1 = (size_t)1 * 1024 * 1024;
        float* fh  = ws;
        float* hn  = fh + M4;
        float* q   = hn + M4;
        float* kb  = q  + M4;
        float* vb  = kb + M1;
        float* gb  = vb + M1;
        float* ub  = gb + M4;
        unsigned short* fvt = (unsigned short*)(ub + M4);

        k_gather<<<SEQ, 256, 0, stream>>>(ids, embed, fh);

        for (int i = 0; i < NLAYERS; i++) {
            const float* Wq_i = Wq + (size_t)i * HDIM * HDIM;
            const float* Wk_i = Wk + (size_t)i * 512 * HDIM;
            const float* Wv_i = Wv + (size_t)i * 512 * HDIM;
            const float* Wo_i = Wo + (size_t)i * HDIM * HDIM;
            const float* Wg_i = Wg + (size_t)i * FDIM * HDIM;
            const float* Wu_i = Wu + (size_t)i * FDIM * HDIM;
            const float* Wd_i = Wd + (size_t)i * HDIM * FDIM;

            k_rmsnorm_f32<<<SEQ, 256, 0, stream>>>(hn, fh, ln1 + i * HDIM);
            k_gemm<false><<<dim3(16, 16), 256, 0, stream>>>(hn, Wq_i, q,  HDIM, HDIM, HDIM, HDIM);
            k_gemm<false><<<dim3(4, 16),  256, 0, stream>>>(hn, Wk_i, kb, HDIM, HDIM, HDIM, 512);
            k_gemm<false><<<dim3(4, 16),  256, 0, stream>>>(hn, Wv_i, vb, HDIM, HDIM, HDIM, 512);
            k_rope<<<SEQ, 256, 0, stream>>>(q,  NHEADS, 0.125f, HDIM);
            k_rope<<<SEQ, 256, 0, stream>>>(kb, KVH,    1.0f,  512);
            k_vtrans<<<dim3(SEQ/64, 8), 256, 0, stream>>>(vb, 512, fvt);
            k_attn_f32<<<dim3(SEQ/64, NHEADS), 256, 0, stream>>>(q, HDIM, kb, 512, fvt);
            k_gemm<true><<<dim3(16, 16), 256, 0, stream>>>(q, Wo_i, fh, HDIM, HDIM, HDIM, HDIM);

            k_rmsnorm_f32<<<SEQ, 256, 0, stream>>>(hn, fh, ln2 + i * HDIM);
            for (int fc = 0; fc < 4; fc++) {
                const float* Wg_c = Wg_i + (size_t)fc * 2048 * HDIM;
                const float* Wu_c = Wu_i + (size_t)fc * 2048 * HDIM;
                const float* Wd_c = Wd_i + (size_t)fc * 2048;
                k_gemm<false><<<dim3(16, 16), 256, 0, stream>>>(hn, Wg_c, gb, HDIM, HDIM, HDIM, 2048);
                k_gemm<false><<<dim3(16, 16), 256, 0, stream>>>(hn, Wu_c, ub, HDIM, HDIM, HDIM, 2048);
                k_silu<<<4096, 256, 0, stream>>>(gb, ub);
                k_gemm<true><<<dim3(16, 16), 256, 0, stream>>>(gb, Wd_c, fh, 2048, 2048, FDIM, HDIM);
            }
        }

        k_rmsnorm_f32<<<SEQ, 256, 0, stream>>>(hn, fh, fln);
        k_gemm<false><<<dim3(VOCAB/128, 16), 256, 0, stream>>>(hn, embed, out, HDIM, HDIM, HDIM, VOCAB);
    }
}